// Round 1
// baseline (495.391 us; speedup 1.0000x reference)
//
#include <hip/hip_runtime.h>
#include <hip/hip_bf16.h>

#define NROWS 8192
#define DIM   1024
#define THRESH 0.85f

typedef __attribute__((ext_vector_type(4))) float f32x4;
typedef __attribute__((ext_vector_type(8))) short bf16x8;

__device__ __forceinline__ short f2bf(float x) {
    union { float f; unsigned u; } c; c.f = x;
    unsigned r = c.u + 0x7FFFu + ((c.u >> 16) & 1u);
    return (short)(r >> 16);
}

__device__ __forceinline__ void async16(const void* g, void* l) {
    __builtin_amdgcn_global_load_lds(
        (const __attribute__((address_space(1))) void*)g,
        (__attribute__((address_space(3))) void*)l, 16, 0, 0);
}

// ---------------- elementwise / prep kernels (unchanged) ----------------

__global__ __launch_bounds__(256) void f32_to_bf16_k(const float* __restrict__ in,
                                                     short* __restrict__ out, int n) {
    int i = (blockIdx.x * 256 + threadIdx.x) * 4;
    if (i < n) {
        float4 v = *(const float4*)(in + i);
        short4 o;
        o.x = f2bf(v.x); o.y = f2bf(v.y); o.z = f2bf(v.z); o.w = f2bf(v.w);
        *(short4*)(out + i) = o;
    }
}

__global__ __launch_bounds__(256) void transpose_to_bf16_k(const float* __restrict__ in,
                                                           short* __restrict__ out, int dim) {
    __shared__ float tile[32][33];
    int bx = blockIdx.x * 32, by = blockIdx.y * 32;
    int tx = threadIdx.x, ty = threadIdx.y;
    for (int r = ty; r < 32; r += 8) tile[r][tx] = in[(size_t)(by + r) * dim + bx + tx];
    __syncthreads();
    for (int r = ty; r < 32; r += 8) out[(size_t)(bx + r) * dim + by + tx] = f2bf(tile[tx][r]);
}

__global__ void zero_f32_k(float* p, int n) {
    int i = blockIdx.x * blockDim.x + threadIdx.x;
    if (i < n) p[i] = 0.f;
}

__global__ __launch_bounds__(256) void ln_gelu_k(const float* __restrict__ h,
                                                 const float* __restrict__ gamma,
                                                 const float* __restrict__ beta,
                                                 short* __restrict__ g) {
    int row = blockIdx.x, t = threadIdx.x;
    const float* x = h + (size_t)row * DIM;
    float lv[4], s = 0.f, ss = 0.f;
    #pragma unroll
    for (int i = 0; i < 4; i++) {
        float v = x[t + i * 256];
        lv[i] = v; s += v; ss += v * v;
    }
    #pragma unroll
    for (int o = 32; o; o >>= 1) { s += __shfl_down(s, o, 64); ss += __shfl_down(ss, o, 64); }
    __shared__ float red[8];
    if ((t & 63) == 0) { red[(t >> 6) * 2] = s; red[(t >> 6) * 2 + 1] = ss; }
    __syncthreads();
    s  = red[0] + red[2] + red[4] + red[6];
    ss = red[1] + red[3] + red[5] + red[7];
    float mu = s * (1.0f / DIM);
    float var = ss * (1.0f / DIM) - mu * mu;
    float rstd = rsqrtf(var + 1e-5f);
    short* go = g + (size_t)row * DIM;
    #pragma unroll
    for (int i = 0; i < 4; i++) {
        int c = t + i * 256;
        float v = (lv[i] - mu) * rstd * gamma[c] + beta[c];
        float ge = 0.5f * v * (1.0f + erff(v * 0.70710678118654752f));
        go[c] = f2bf(ge);
    }
}

__global__ __launch_bounds__(256) void rownorm_bf16_k(const float* __restrict__ enc,
                                                      short* __restrict__ out) {
    int row = blockIdx.x, t = threadIdx.x;
    const float* x = enc + (size_t)row * DIM;
    float lv[4], ss = 0.f;
    #pragma unroll
    for (int i = 0; i < 4; i++) {
        float v = x[t + i * 256];
        lv[i] = v; ss += v * v;
    }
    #pragma unroll
    for (int o = 32; o; o >>= 1) ss += __shfl_down(ss, o, 64);
    __shared__ float red[4];
    if ((t & 63) == 0) red[t >> 6] = ss;
    __syncthreads();
    ss = red[0] + red[1] + red[2] + red[3];
    float inv = 1.0f / fmaxf(sqrtf(ss), 1e-12f);
    short* go = out + (size_t)row * DIM;
    #pragma unroll
    for (int i = 0; i < 4; i++) go[t + i * 256] = f2bf(lv[i] * inv);
}

// ---------------- 128x128 MFMA GEMM (dense passes, unchanged) ----------------
__global__ __launch_bounds__(256) void gemm_bt_k(const short* __restrict__ A,
                                                 const short* __restrict__ Bt,
                                                 float* __restrict__ C,
                                                 const float* __restrict__ bias,
                                                 float* __restrict__ dup,
                                                 int M, int Nmat, int K, int mode) {
    __shared__ __align__(16) char smraw[17024];
    short* smA = (short*)smraw;
    short* smB = smA + 128 * 32;
    float* epi = (float*)smraw;

    int bm, bn;
    if (mode == 1) {
        const int NB = Nmat >> 7;
        int bid = blockIdx.x, r = 0, off = 0;
        while (off + (NB - r) <= bid) { off += NB - r; r++; }
        bm = r; bn = r + (bid - off);
    } else {
        bn = blockIdx.x; bm = blockIdx.y;
    }
    const int tileN = bn * 128;
    const int tileM = bm * 128;

    const int t = threadIdx.x;
    const int wave = t >> 6;
    const int wm = wave >> 1, wn = wave & 1;
    const int l = t & 63;

    const int sr = t >> 2;
    const int swr = (sr & 3) ^ ((sr >> 2) & 3);
    const int cg = (((t & 3) ^ swr) & 3) * 8;
    const size_t aOff = (size_t)(tileM + sr) * K + cg;
    const size_t bOff = (size_t)(tileN + sr) * K + cg;
    const int ldsOff = t * 8;

    f32x4 acc[4][4];
    #pragma unroll
    for (int i = 0; i < 4; i++)
        #pragma unroll
        for (int j = 0; j < 4; j++) acc[i][j] = (f32x4){0.f, 0.f, 0.f, 0.f};

    const int lr = l & 15;
    const int lq = l >> 4;
    const int sw = (lr & 3) ^ ((lr >> 2) & 3);
    const int kg = (lq ^ sw) & 3;
    const int aBase = (wm * 64 + lr) * 32 + kg * 8;
    const int bBase = (wn * 64 + lr) * 32 + kg * 8;

    for (int k0 = 0; k0 < K; k0 += 32) {
        __syncthreads();
        async16(A + aOff + k0,                   smA + ldsOff);
        async16(A + aOff + (size_t)64 * K + k0,  smA + ldsOff + 64 * 32);
        async16(Bt + bOff + k0,                  smB + ldsOff);
        async16(Bt + bOff + (size_t)64 * K + k0, smB + ldsOff + 64 * 32);
        __syncthreads();

        bf16x8 af[4], bfr[4];
        #pragma unroll
        for (int i = 0; i < 4; i++) af[i] = *(const bf16x8*)(smA + aBase + i * 16 * 32);
        #pragma unroll
        for (int j = 0; j < 4; j++) bfr[j] = *(const bf16x8*)(smB + bBase + j * 16 * 32);
        #pragma unroll
        for (int i = 0; i < 4; i++)
            #pragma unroll
            for (int j = 0; j < 4; j++)
                acc[i][j] = __builtin_amdgcn_mfma_f32_16x16x32_bf16(af[i], bfr[j], acc[i][j], 0, 0, 0);
    }

    for (int ch = 0; ch < 4; ch++) {
        __syncthreads();
        #pragma unroll
        for (int j = 0; j < 4; j++) {
            const int cl = wn * 64 + j * 16 + lr;
            const float bj = bias ? bias[tileN + cl] : 0.f;
            #pragma unroll
            for (int r = 0; r < 4; r++) {
                const int rl = wm * 16 + lq * 4 + r;
                epi[rl * 132 + cl] = acc[ch][j][r] + bj;
            }
        }
        __syncthreads();
        #pragma unroll
        for (int k = 0; k < 4; k++) {
            const int v = k * 256 + t;
            const int rl = v >> 5;
            const int c4 = (v & 31) * 4;
            float4 vec = *(float4*)&epi[rl * 132 + c4];
            const int grow = tileM + (rl < 16 ? ch * 16 + rl : 48 + ch * 16 + rl);
            const int gcol = tileN + c4;
            *(float4*)&C[(size_t)grow * Nmat + gcol] = vec;
            if (mode == 1) {
                if (vec.x > THRESH && grow < gcol)     dup[gcol]     = 1.f;
                if (vec.y > THRESH && grow < gcol + 1) dup[gcol + 1] = 1.f;
                if (vec.z > THRESH && grow < gcol + 2) dup[gcol + 2] = 1.f;
                if (vec.w > THRESH && grow < gcol + 3) dup[gcol + 3] = 1.f;
            }
        }
    }

    if (mode == 1 && bm != bn) {
        const int mr = wn * 16 + lr;
        for (int ch = 0; ch < 4; ch++) {
            __syncthreads();
            #pragma unroll
            for (int i = 0; i < 4; i++) {
                #pragma unroll
                for (int r = 0; r < 4; r++) {
                    const int mc = wm * 64 + i * 16 + lq * 4 + r;
                    epi[mr * 132 + mc] = acc[i][ch][r];
                }
            }
            __syncthreads();
            #pragma unroll
            for (int k = 0; k < 4; k++) {
                const int v = k * 256 + t;
                const int rl = v >> 5;
                const int c4 = (v & 31) * 4;
                float4 vec = *(float4*)&epi[rl * 132 + c4];
                const int orow = tileN + ch * 16 + (rl < 16 ? rl : 48 + rl);
                *(float4*)&C[(size_t)orow * Nmat + tileM + c4] = vec;
            }
        }
    }
}

// ---------------- 256x256 8-phase triangular sim GEMM (T2+T3+T4+T5) ----------------
// 8 waves (2M x 4N), per-wave 128x64 output, BK=64 split into two K-halves of 32.
// LDS: A[2 dbuf][2 kh][256 rows][32 k] bf16 + B same = 128 KiB (dynamic).
// Swizzle: LDS slot (16B) s of row r holds k-group (s ^ (r&3)); staged via
// pre-swizzled global source (linear global_load_lds dest), read with same XOR.
// Counted vmcnt(4) at phases 4 and 8 only (2 half-tiles = 4 loads in flight
// after each wait); buffer-region free/issue schedule derived so each region's
// staging is issued strictly after its last reader phase's end-barrier.

#define BARF()   do { asm volatile("" ::: "memory"); __builtin_amdgcn_s_barrier(); asm volatile("" ::: "memory"); } while (0)
#define LGKM0()  asm volatile("s_waitcnt lgkmcnt(0)" ::: "memory")
#define VMCNT(n) asm volatile("s_waitcnt vmcnt(" #n ")" ::: "memory")

__global__ __launch_bounds__(512, 2) void gemm256_tri_k(const short* __restrict__ E,
                                                        float* __restrict__ C,
                                                        float* __restrict__ dup,
                                                        int Nrows, int K) {
    extern __shared__ __align__(16) char smraw[];
    short* smA = (short*)smraw;       // 2*2*256*32 shorts = 65536 B
    short* smB = smA + 32768;         // + 65536 B
    float* epi = (float*)smraw;       // epilogue reuse: 64 x 260 f32 = 66560 B

    // triangular block decode (upper triangle incl. diagonal)
    const int NBT = Nrows >> 8;
    int bid = blockIdx.x;
    int r = 0, off = 0;
    while (off + (NBT - r) <= bid) { off += NBT - r; r++; }
    const int bm = r, bn = r + (bid - off);
    const int tileM = bm << 8, tileN = bn << 8;

    const int t = threadIdx.x;
    const int wave = t >> 6;
    const int wm = wave >> 2, wn = wave & 3;
    const int l = t & 63;
    const int lr = l & 15, lq = l >> 4;

    // staging: thread t -> LDS bytes t*16 (wave-uniform + lane*16). Row = j*128 + (t>>2),
    // slot = t&3. Pre-swizzle SOURCE k-group so LDS holds slot^=row&3 layout.
    const int srow  = t >> 2;
    const int sslot = ((t & 3) ^ ((t >> 2) & 3)) * 8;   // elements
    const short* aS0 = E + (size_t)(tileM + srow) * K + sslot;
    const short* aS1 = aS0 + (size_t)128 * K;
    const short* bS0 = E + (size_t)(tileN + srow) * K + sslot;
    const short* bS1 = bS0 + (size_t)128 * K;
    const int ldst = t * 8;                             // shorts

    // fragment reads: row stride 32 shorts (64 B); slot = lq ^ (lr&3)  (content = k-group lq)
    const int swz  = (lq ^ (lr & 3)) * 8;
    const int aoff = (wm * 128 + lr) * 32 + swz;
    const int boff = (wn * 64  + lr) * 32 + swz;

    f32x4 acc[8][4];
    #pragma unroll
    for (int i = 0; i < 8; i++)
        #pragma unroll
        for (int j = 0; j < 4; j++) acc[i][j] = (f32x4){0.f, 0.f, 0.f, 0.f};

#define STAGE_A(DB, KH, KC) do { \
    short* d_ = smA + (DB) * 16384 + (KH) * 8192 + ldst; \
    async16(aS0 + (KC), d_); async16(aS1 + (KC), d_ + 4096); } while (0)
#define STAGE_B(DB, KH, KC) do { \
    short* d_ = smB + (DB) * 16384 + (KH) * 8192 + ldst; \
    async16(bS0 + (KC), d_); async16(bS1 + (KC), d_ + 4096); } while (0)

#define PH_AB(DB, KS, MB) do { \
    const short* Ab_ = smA + (DB) * 16384 + (KS) * 8192 + aoff; \
    const short* Bb_ = smB + (DB) * 16384 + (KS) * 8192 + boff; \
    af[0] = *(const bf16x8*)(Ab_ + ((MB) + 0) * 512); \
    af[1] = *(const bf16x8*)(Ab_ + ((MB) + 1) * 512); \
    af[2] = *(const bf16x8*)(Ab_ + ((MB) + 2) * 512); \
    af[3] = *(const bf16x8*)(Ab_ + ((MB) + 3) * 512); \
    bfr[0] = *(const bf16x8*)(Bb_ + 0);    \
    bfr[1] = *(const bf16x8*)(Bb_ + 512);  \
    bfr[2] = *(const bf16x8*)(Bb_ + 1024); \
    bfr[3] = *(const bf16x8*)(Bb_ + 1536); } while (0)

#define PH_A(DB, KS, MB) do { \
    const short* Ab_ = smA + (DB) * 16384 + (KS) * 8192 + aoff; \
    af[0] = *(const bf16x8*)(Ab_ + ((MB) + 0) * 512); \
    af[1] = *(const bf16x8*)(Ab_ + ((MB) + 1) * 512); \
    af[2] = *(const bf16x8*)(Ab_ + ((MB) + 2) * 512); \
    af[3] = *(const bf16x8*)(Ab_ + ((MB) + 3) * 512); } while (0)

#define MFMA16(MB) do { \
    __builtin_amdgcn_s_setprio(1); \
    _Pragma("unroll") for (int m_ = 0; m_ < 4; m_++) \
        _Pragma("unroll") for (int n_ = 0; n_ < 4; n_++) \
            acc[(MB) + m_][n_] = __builtin_amdgcn_mfma_f32_16x16x32_bf16(af[m_], bfr[n_], acc[(MB) + m_][n_], 0, 0, 0); \
    __builtin_amdgcn_s_setprio(0); } while (0)

    bf16x8 af[4], bfr[4];

    // prologue: tile0 (both k-halves) -> dbuf0; tile1 kh0 -> dbuf1.
    // 12 loads issued; vmcnt(4) completes tile0's 8, leaves tile1.kh0 (4) in flight.
    STAGE_A(0, 0, 0);  STAGE_B(0, 0, 0);
    STAGE_A(0, 1, 32); STAGE_B(0, 1, 32);
    STAGE_A(1, 0, 64); STAGE_B(1, 0, 64);
    VMCNT(4);
    BARF();

    const int NIT = K >> 7;   // iterations of 2 K-tiles (BK=64 each)
    for (int it = 0; it < NIT - 1; ++it) {
        const int kb = it * 128;
        // ph1: compute dbuf0 kh0 mlo | stage (a+1).A kh1
        PH_AB(0, 0, 0); STAGE_A(1, 1, kb + 96);  BARF(); LGKM0(); MFMA16(0); BARF();
        // ph2: dbuf0 kh0 mhi | stage (a+1).B kh1
        PH_A (0, 0, 4); STAGE_B(1, 1, kb + 96);  BARF(); LGKM0(); MFMA16(4); BARF();
        // ph3: dbuf0 kh1 mlo | stage (a+2).A kh0 (dbuf0.kh0 free after ph2)
        PH_AB(0, 1, 0); STAGE_A(0, 0, kb + 128); BARF(); LGKM0(); MFMA16(0); BARF();
        // ph4: dbuf0 kh1 mhi | stage (a+2).B kh0 | vmcnt(4): (a+1) fully landed
        PH_A (0, 1, 4); STAGE_B(0, 0, kb + 128); BARF(); LGKM0(); MFMA16(4); VMCNT(4); BARF();
        // ph5: dbuf1 kh0 mlo | stage (a+2).A kh1
        PH_AB(1, 0, 0); STAGE_A(0, 1, kb + 160); BARF(); LGKM0(); MFMA16(0); BARF();
        // ph6: dbuf1 kh0 mhi | stage (a+2).B kh1
        PH_A (1, 0, 4); STAGE_B(0, 1, kb + 160); BARF(); LGKM0(); MFMA16(4); BARF();
        // ph7: dbuf1 kh1 mlo | stage (a+3).A kh0
        PH_AB(1, 1, 0); STAGE_A(1, 0, kb + 192); BARF(); LGKM0(); MFMA16(0); BARF();
        // ph8: dbuf1 kh1 mhi | stage (a+3).B kh0 | vmcnt(4): (a+2) fully landed
        PH_A (1, 1, 4); STAGE_B(1, 0, kb + 192); BARF(); LGKM0(); MFMA16(4); VMCNT(4); BARF();
    }
    {   // final iteration (tiles NT-2, NT-1): only (NT-1).kh1 left to stage
        const int kb = (NIT - 1) * 128;
        PH_AB(0, 0, 0); STAGE_A(1, 1, kb + 96);  BARF(); LGKM0(); MFMA16(0); BARF();
        PH_A (0, 0, 4); STAGE_B(1, 1, kb + 96);  BARF(); LGKM0(); MFMA16(4); BARF();
        PH_AB(0, 1, 0);                          BARF(); LGKM0(); MFMA16(0); BARF();
        PH_A (0, 1, 4);                          BARF(); LGKM0(); MFMA16(4); VMCNT(0); BARF();
        PH_AB(1, 0, 0);                          BARF(); LGKM0(); MFMA16(0); BARF();
        PH_A (1, 0, 4);                          BARF(); LGKM0(); MFMA16(4); BARF();
        PH_AB(1, 1, 0);                          BARF(); LGKM0(); MFMA16(0); BARF();
        PH_A (1, 1, 4);                          BARF(); LGKM0(); MFMA16(4); BARF();
    }

#undef STAGE_A
#undef STAGE_B
#undef PH_AB
#undef PH_A
#undef MFMA16

    // ---- epilogue: normal orientation, 4 rounds of 64 rows x 256 cols ----
    __syncthreads();
    for (int rr = 0; rr < 4; rr++) {
        if ((rr >> 1) == wm) {
            const int mb = (rr & 1) * 4;
            #pragma unroll
            for (int m = 0; m < 4; m++)
                #pragma unroll
                for (int n = 0; n < 4; n++)
                    #pragma unroll
                    for (int q = 0; q < 4; q++)
                        epi[(m * 16 + lq * 4 + q) * 260 + wn * 64 + n * 16 + lr] = acc[mb + m][n][q];
        }
        __syncthreads();
        #pragma unroll
        for (int k2 = 0; k2 < 8; k2++) {
            const int v = k2 * 512 + t;
            const int rl = v >> 6;
            const int c4 = (v & 63) * 4;
            float4 vec = *(float4*)&epi[rl * 260 + c4];
            const int grow = tileM + rr * 64 + rl;
            const int gcol = tileN + c4;
            *(float4*)&C[(size_t)grow * Nrows + gcol] = vec;
            if (vec.x > THRESH && grow < gcol)     dup[gcol]     = 1.f;
            if (vec.y > THRESH && grow < gcol + 1) dup[gcol + 1] = 1.f;
            if (vec.z > THRESH && grow < gcol + 2) dup[gcol + 2] = 1.f;
            if (vec.w > THRESH && grow < gcol + 3) dup[gcol + 3] = 1.f;
        }
        __syncthreads();
    }

    // ---- mirrored writes for off-diagonal blocks (always row > col: no dup checks) ----
    if (bm != bn) {
        for (int cc = 0; cc < 4; cc++) {
            if (wn == cc) {
                #pragma unroll
                for (int i2 = 0; i2 < 8; i2++)
                    #pragma unroll
                    for (int n = 0; n < 4; n++)
                        #pragma unroll
                        for (int q = 0; q < 4; q++)
                            epi[(n * 16 + lr) * 260 + wm * 128 + i2 * 16 + lq * 4 + q] = acc[i2][n][q];
            }
            __syncthreads();
            #pragma unroll
            for (int k2 = 0; k2 < 8; k2++) {
                const int v = k2 * 512 + t;
                const int rl = v >> 6;
                const int c4 = (v & 63) * 4;
                float4 vec = *(float4*)&epi[rl * 260 + c4];
                *(float4*)&C[(size_t)(tileN + cc * 64 + rl) * Nrows + tileM + c4] = vec;
            }
            __syncthreads();
        }
    }
}

// ---------------- launch ----------------

extern "C" void kernel_launch(void* const* d_in, const int* in_sizes, int n_in,
                              void* d_out, int out_size, void* d_ws, size_t ws_size,
                              hipStream_t stream) {
    const float* summaries = (const float*)d_in[0];
    const float* W1    = (const float*)d_in[1];
    const float* b1    = (const float*)d_in[2];
    const float* gamma = (const float*)d_in[3];
    const float* beta  = (const float*)d_in[4];
    const float* W2    = (const float*)d_in[5];
    const float* b2    = (const float*)d_in[6];

    float* sim = (float*)d_out;
    float* dup = sim + (size_t)NROWS * NROWS;

    char* ws = (char*)d_ws;
    float* hbuf = (float*)ws;                              // 32 MB: h, then enc
    short* xb   = (short*)(ws + (size_t)32 * 1024 * 1024); // 16 MB: Xb, then encb
    short* gbuf = (short*)(ws + (size_t)48 * 1024 * 1024); // 16 MB: g
    short* w1t  = (short*)(ws + (size_t)64 * 1024 * 1024); // 2 MB
    short* w2t  = (short*)(ws + (size_t)66 * 1024 * 1024); // 2 MB

    static int tri_init = 0;
    if (!tri_init) {
        hipFuncSetAttribute(reinterpret_cast<const void*>(gemm256_tri_k),
                            hipFuncAttributeMaxDynamicSharedMemorySize, 131072);
        tri_init = 1;
    }

    f32_to_bf16_k<<<dim3(NROWS * DIM / 1024), dim3(256), 0, stream>>>(summaries, xb, NROWS * DIM);
    transpose_to_bf16_k<<<dim3(32, 32), dim3(32, 8), 0, stream>>>(W1, w1t, DIM);
    transpose_to_bf16_k<<<dim3(32, 32), dim3(32, 8), 0, stream>>>(W2, w2t, DIM);
    zero_f32_k<<<dim3(32), dim3(256), 0, stream>>>(dup, NROWS);

    // h = X @ W1 + b1
    gemm_bt_k<<<dim3(DIM / 128, NROWS / 128), dim3(256), 0, stream>>>(
        xb, w1t, hbuf, b1, (float*)nullptr, NROWS, DIM, DIM, 0);
    // g = gelu(layernorm(h))
    ln_gelu_k<<<dim3(NROWS), dim3(256), 0, stream>>>(hbuf, gamma, beta, gbuf);
    // enc = g @ W2 + b2
    gemm_bt_k<<<dim3(DIM / 128, NROWS / 128), dim3(256), 0, stream>>>(
        gbuf, w2t, hbuf, b2, (float*)nullptr, NROWS, DIM, DIM, 0);
    // encb = normalize(enc) in bf16
    rownorm_bf16_k<<<dim3(NROWS), dim3(256), 0, stream>>>(hbuf, xb);
    // sim = encb @ encb^T : 256^2 8-phase triangular tiles, mirrored writes, fused dup
    const int NBT = NROWS / 256;
    gemm256_tri_k<<<dim3(NBT * (NBT + 1) / 2), dim3(512), 131072, stream>>>(
        xb, sim, dup, NROWS, DIM);
}

// Round 2
// 480.917 us; speedup vs baseline: 1.0301x; 1.0301x over previous
//
#include <hip/hip_runtime.h>
#include <hip/hip_bf16.h>

#define NROWS 8192
#define DIM   1024
#define THRESH 0.85f

typedef __attribute__((ext_vector_type(4))) float f32x4;
typedef __attribute__((ext_vector_type(8))) short bf16x8;

__device__ __forceinline__ short f2bf(float x) {
    union { float f; unsigned u; } c; c.f = x;
    unsigned r = c.u + 0x7FFFu + ((c.u >> 16) & 1u);
    return (short)(r >> 16);
}

__device__ __forceinline__ void async16(const void* g, void* l) {
    __builtin_amdgcn_global_load_lds(
        (const __attribute__((address_space(1))) void*)g,
        (__attribute__((address_space(3))) void*)l, 16, 0, 0);
}

// ---------------- elementwise / prep kernels ----------------

__global__ __launch_bounds__(256) void f32_to_bf16_k(const float* __restrict__ in,
                                                     short* __restrict__ out, int n) {
    int i = (blockIdx.x * 256 + threadIdx.x) * 4;
    if (i < n) {
        float4 v = *(const float4*)(in + i);
        short4 o;
        o.x = f2bf(v.x); o.y = f2bf(v.y); o.z = f2bf(v.z); o.w = f2bf(v.w);
        *(short4*)(out + i) = o;
    }
}

__global__ __launch_bounds__(256) void transpose_to_bf16_k(const float* __restrict__ in,
                                                           short* __restrict__ out, int dim) {
    __shared__ float tile[32][33];
    int bx = blockIdx.x * 32, by = blockIdx.y * 32;
    int tx = threadIdx.x, ty = threadIdx.y;
    for (int r = ty; r < 32; r += 8) tile[r][tx] = in[(size_t)(by + r) * dim + bx + tx];
    __syncthreads();
    for (int r = ty; r < 32; r += 8) out[(size_t)(bx + r) * dim + by + tx] = f2bf(tile[tx][r]);
}

__global__ void zero_f32_k(float* p, int n) {
    int i = blockIdx.x * blockDim.x + threadIdx.x;
    if (i < n) p[i] = 0.f;
}

// LayerNorm + exact GELU + bf16 cast, one row per block, float4 loads (G13).
__global__ __launch_bounds__(256) void ln_gelu_k(const float* __restrict__ h,
                                                 const float* __restrict__ gamma,
                                                 const float* __restrict__ beta,
                                                 short* __restrict__ g) {
    int row = blockIdx.x, t = threadIdx.x;
    const float* x = h + (size_t)row * DIM;
    float4 v4 = *(const float4*)(x + t * 4);
    float s = v4.x + v4.y + v4.z + v4.w;
    float ss = v4.x * v4.x + v4.y * v4.y + v4.z * v4.z + v4.w * v4.w;
    #pragma unroll
    for (int o = 32; o; o >>= 1) { s += __shfl_down(s, o, 64); ss += __shfl_down(ss, o, 64); }
    __shared__ float red[8];
    if ((t & 63) == 0) { red[(t >> 6) * 2] = s; red[(t >> 6) * 2 + 1] = ss; }
    __syncthreads();
    s  = red[0] + red[2] + red[4] + red[6];
    ss = red[1] + red[3] + red[5] + red[7];
    float mu = s * (1.0f / DIM);
    float var = ss * (1.0f / DIM) - mu * mu;
    float rstd = rsqrtf(var + 1e-5f);
    float4 g4 = *(const float4*)(gamma + t * 4);
    float4 b4 = *(const float4*)(beta + t * 4);
    float vv[4] = {v4.x, v4.y, v4.z, v4.w};
    float gg[4] = {g4.x, g4.y, g4.z, g4.w};
    float bb[4] = {b4.x, b4.y, b4.z, b4.w};
    short4 o;
    short* op = (short*)&o;
    #pragma unroll
    for (int i = 0; i < 4; i++) {
        float v = (vv[i] - mu) * rstd * gg[i] + bb[i];
        float ge = 0.5f * v * (1.0f + erff(v * 0.70710678118654752f));
        op[i] = f2bf(ge);
    }
    *(short4*)(g + (size_t)row * DIM + t * 4) = o;
}

// L2 row-normalize + bf16 cast, float4 loads.
__global__ __launch_bounds__(256) void rownorm_bf16_k(const float* __restrict__ enc,
                                                      short* __restrict__ out) {
    int row = blockIdx.x, t = threadIdx.x;
    const float* x = enc + (size_t)row * DIM;
    float4 v4 = *(const float4*)(x + t * 4);
    float ss = v4.x * v4.x + v4.y * v4.y + v4.z * v4.z + v4.w * v4.w;
    #pragma unroll
    for (int o = 32; o; o >>= 1) ss += __shfl_down(ss, o, 64);
    __shared__ float red[4];
    if ((t & 63) == 0) red[t >> 6] = ss;
    __syncthreads();
    ss = red[0] + red[1] + red[2] + red[3];
    float inv = 1.0f / fmaxf(sqrtf(ss), 1e-12f);
    short4 o;
    o.x = f2bf(v4.x * inv); o.y = f2bf(v4.y * inv);
    o.z = f2bf(v4.z * inv); o.w = f2bf(v4.w * inv);
    *(short4*)(out + (size_t)row * DIM + t * 4) = o;
}

#define BARF()   do { asm volatile("" ::: "memory"); __builtin_amdgcn_s_barrier(); asm volatile("" ::: "memory"); } while (0)
#define LGKM0()  asm volatile("s_waitcnt lgkmcnt(0)" ::: "memory")
#define VMCNT(n) asm volatile("s_waitcnt vmcnt(" #n ")" ::: "memory")

// ---------------- dense pipelined GEMM: C[M][N] = A[M][K] @ Bt[N][K]^T + bias ----------------
// BM=128, BN=256, BK=64 (two K-halves of 32). 512 threads = 8 waves (2M x 4N),
// per-wave 64x64 output, acc[4][4]. 4-phase iteration over 2 K-tiles, counted vmcnt(6):
// each phase issues ONE half-K item (A:1 + B:2 loads/thread) with 3-phase slack;
// vmcnt(6) (= 2 items in flight) drains exactly the item consumed next phase.
// LDS: A[2][2][128][32] 32 KiB + B[2][2][256][32] 64 KiB = 96 KiB; epi reuse 32x260 f32.
// Grid (N/256, M/128) = (4, 64) = 256 blocks = exactly 1/CU, zero tail.
__global__ __launch_bounds__(512, 2) void gemm_dense256_k(const short* __restrict__ A,
                                                          const short* __restrict__ Bt,
                                                          float* __restrict__ C,
                                                          const float* __restrict__ bias,
                                                          int M, int Nmat, int K) {
    extern __shared__ __align__(16) char smraw[];
    short* smA = (short*)smraw;        // 2*2*128*32 shorts = 32 KiB
    short* smB = smA + 16384;          // 2*2*256*32 shorts = 64 KiB
    float* epi = (float*)smraw;        // epilogue reuse: 32 x 260 f32

    const int tileN = blockIdx.x << 8;
    const int tileM = blockIdx.y << 7;

    const int t = threadIdx.x;
    const int wave = t >> 6;
    const int wm = wave >> 2, wn = wave & 3;   // 2M x 4N
    const int l = t & 63;
    const int lr = l & 15, lq = l >> 4;

    // staging: thread t -> row t>>2 (0..127 per unit), slot t&3; source k-group pre-swizzled.
    const int srow  = t >> 2;
    const int sslot = ((t & 3) ^ ((t >> 2) & 3)) * 8;
    const short* aS  = A  + (size_t)(tileM + srow) * K + sslot;
    const short* bS0 = Bt + (size_t)(tileN + srow) * K + sslot;
    const short* bS1 = bS0 + (size_t)128 * K;
    const int t8 = t * 8;

    // fragment reads: row stride 32 shorts; slot = lq ^ (lr&3)
    const int swz  = (lq ^ (lr & 3)) * 8;
    const int aoff = (wm * 64 + lr) * 32 + swz;
    const int boff = (wn * 64 + lr) * 32 + swz;

    f32x4 acc[4][4];
    #pragma unroll
    for (int i = 0; i < 4; i++)
        #pragma unroll
        for (int j = 0; j < 4; j++) acc[i][j] = (f32x4){0.f, 0.f, 0.f, 0.f};

#define DSTAGE(DB, KH, KC) do { \
    short* da_ = smA + (DB) * 8192 + (KH) * 4096 + t8; \
    async16(aS + (KC), da_); \
    short* db_ = smB + (DB) * 16384 + (KH) * 8192 + t8; \
    async16(bS0 + (KC), db_); async16(bS1 + (KC), db_ + 4096); } while (0)

#define DPH(DB, KH) do { \
    const short* Ab_ = smA + (DB) * 8192 + (KH) * 4096 + aoff; \
    const short* Bb_ = smB + (DB) * 16384 + (KH) * 8192 + boff; \
    af[0] = *(const bf16x8*)(Ab_ + 0);    af[1] = *(const bf16x8*)(Ab_ + 512); \
    af[2] = *(const bf16x8*)(Ab_ + 1024); af[3] = *(const bf16x8*)(Ab_ + 1536); \
    bfr[0] = *(const bf16x8*)(Bb_ + 0);    bfr[1] = *(const bf16x8*)(Bb_ + 512); \
    bfr[2] = *(const bf16x8*)(Bb_ + 1024); bfr[3] = *(const bf16x8*)(Bb_ + 1536); } while (0)

#define DMFMA16() do { \
    __builtin_amdgcn_s_setprio(1); \
    _Pragma("unroll") for (int m_ = 0; m_ < 4; m_++) \
        _Pragma("unroll") for (int n_ = 0; n_ < 4; n_++) \
            acc[m_][n_] = __builtin_amdgcn_mfma_f32_16x16x32_bf16(af[m_], bfr[n_], acc[m_][n_], 0, 0, 0); \
    __builtin_amdgcn_s_setprio(0); } while (0)

    bf16x8 af[4], bfr[4];

    // prologue: items 0.kh0, 0.kh1, 1.kh0 (9 loads); drain 0.kh0 -> vmcnt(6)
    DSTAGE(0, 0, 0);
    DSTAGE(0, 1, 32);
    DSTAGE(1, 0, 64);
    VMCNT(6);
    BARF();

    const int NIT = K >> 7;  // iterations of 2 K-tiles (BK=64)
    for (int it = 0; it < NIT - 1; ++it) {
        const int kb = it * 128;
        // ph1: compute d0.kh0 | stage (a+1).kh1
        DPH(0, 0); DSTAGE(1, 1, kb + 96);  BARF(); LGKM0(); DMFMA16(); VMCNT(6); BARF();
        // ph2: compute d0.kh1 | stage (a+2).kh0
        DPH(0, 1); DSTAGE(0, 0, kb + 128); BARF(); LGKM0(); DMFMA16(); VMCNT(6); BARF();
        // ph3: compute d1.kh0 | stage (a+2).kh1
        DPH(1, 0); DSTAGE(0, 1, kb + 160); BARF(); LGKM0(); DMFMA16(); VMCNT(6); BARF();
        // ph4: compute d1.kh1 | stage (a+3).kh0
        DPH(1, 1); DSTAGE(1, 0, kb + 192); BARF(); LGKM0(); DMFMA16(); VMCNT(6); BARF();
    }
    {   // final iteration: only (last).kh1 left to stage
        const int kb = (NIT - 1) * 128;
        DPH(0, 0); DSTAGE(1, 1, kb + 96);  BARF(); LGKM0(); DMFMA16(); VMCNT(6); BARF();
        DPH(0, 1);                         BARF(); LGKM0(); DMFMA16(); VMCNT(3); BARF();
        DPH(1, 0);                         BARF(); LGKM0(); DMFMA16(); VMCNT(0); BARF();
        DPH(1, 1);                         BARF(); LGKM0(); DMFMA16();           BARF();
    }

#undef DSTAGE
#undef DPH
#undef DMFMA16

    // epilogue: 4 rounds of 32 rows x 256 cols, fused bias, float4 stores
    float bj[4];
    #pragma unroll
    for (int nb = 0; nb < 4; nb++) bj[nb] = bias[tileN + wn * 64 + nb * 16 + lr];
    __syncthreads();
    for (int rr = 0; rr < 4; rr++) {
        if (wm == (rr >> 1)) {
            #pragma unroll
            for (int h = 0; h < 2; h++) {
                const int mb = (rr & 1) * 2 + h;
                #pragma unroll
                for (int nb = 0; nb < 4; nb++)
                    #pragma unroll
                    for (int q = 0; q < 4; q++)
                        epi[(h * 16 + lq * 4 + q) * 260 + wn * 64 + nb * 16 + lr] = acc[mb][nb][q] + bj[nb];
            }
        }
        __syncthreads();
        #pragma unroll
        for (int k2 = 0; k2 < 4; k2++) {
            const int v = k2 * 512 + t;
            const int rl = v >> 6;
            const int c4 = (v & 63) * 4;
            float4 vec = *(float4*)&epi[rl * 260 + c4];
            *(float4*)&C[(size_t)(tileM + rr * 32 + rl) * Nmat + tileN + c4] = vec;
        }
        __syncthreads();
    }
}

// ---------------- 256x256 8-phase triangular sim GEMM (T1+T2+T3+T4+T5) ----------------

__global__ __launch_bounds__(512, 2) void gemm256_tri_k(const short* __restrict__ E,
                                                        float* __restrict__ C,
                                                        float* __restrict__ dup,
                                                        int Nrows, int K) {
    extern __shared__ __align__(16) char smraw[];
    short* smA = (short*)smraw;       // 2*2*256*32 shorts = 65536 B
    short* smB = smA + 32768;         // + 65536 B
    float* epi = (float*)smraw;       // epilogue reuse: 64 x 260 f32

    // T1: XCD-chunked bijective bid swizzle (exact when nwg % 8 == 0)
    const int NBT = Nrows >> 8;
    const int nwg = (NBT * (NBT + 1)) >> 1;
    int bid = blockIdx.x;
    if (!(nwg & 7)) {
        const int chunk = nwg >> 3;
        bid = (bid & 7) * chunk + (bid >> 3);
    }
    int r = 0, off = 0;
    while (off + (NBT - r) <= bid) { off += NBT - r; r++; }
    const int bm = r, bn = r + (bid - off);
    const int tileM = bm << 8, tileN = bn << 8;

    const int t = threadIdx.x;
    const int wave = t >> 6;
    const int wm = wave >> 2, wn = wave & 3;
    const int l = t & 63;
    const int lr = l & 15, lq = l >> 4;

    const int srow  = t >> 2;
    const int sslot = ((t & 3) ^ ((t >> 2) & 3)) * 8;
    const short* aS0 = E + (size_t)(tileM + srow) * K + sslot;
    const short* aS1 = aS0 + (size_t)128 * K;
    const short* bS0 = E + (size_t)(tileN + srow) * K + sslot;
    const short* bS1 = bS0 + (size_t)128 * K;
    const int ldst = t * 8;

    const int swz  = (lq ^ (lr & 3)) * 8;
    const int aoff = (wm * 128 + lr) * 32 + swz;
    const int boff = (wn * 64  + lr) * 32 + swz;

    f32x4 acc[8][4];
    #pragma unroll
    for (int i = 0; i < 8; i++)
        #pragma unroll
        for (int j = 0; j < 4; j++) acc[i][j] = (f32x4){0.f, 0.f, 0.f, 0.f};

#define STAGE_A(DB, KH, KC) do { \
    short* d_ = smA + (DB) * 16384 + (KH) * 8192 + ldst; \
    async16(aS0 + (KC), d_); async16(aS1 + (KC), d_ + 4096); } while (0)
#define STAGE_B(DB, KH, KC) do { \
    short* d_ = smB + (DB) * 16384 + (KH) * 8192 + ldst; \
    async16(bS0 + (KC), d_); async16(bS1 + (KC), d_ + 4096); } while (0)

#define PH_AB(DB, KS, MB) do { \
    const short* Ab_ = smA + (DB) * 16384 + (KS) * 8192 + aoff; \
    const short* Bb_ = smB + (DB) * 16384 + (KS) * 8192 + boff; \
    af[0] = *(const bf16x8*)(Ab_ + ((MB) + 0) * 512); \
    af[1] = *(const bf16x8*)(Ab_ + ((MB) + 1) * 512); \
    af[2] = *(const bf16x8*)(Ab_ + ((MB) + 2) * 512); \
    af[3] = *(const bf16x8*)(Ab_ + ((MB) + 3) * 512); \
    bfr[0] = *(const bf16x8*)(Bb_ + 0);    \
    bfr[1] = *(const bf16x8*)(Bb_ + 512);  \
    bfr[2] = *(const bf16x8*)(Bb_ + 1024); \
    bfr[3] = *(const bf16x8*)(Bb_ + 1536); } while (0)

#define PH_A(DB, KS, MB) do { \
    const short* Ab_ = smA + (DB) * 16384 + (KS) * 8192 + aoff; \
    af[0] = *(const bf16x8*)(Ab_ + ((MB) + 0) * 512); \
    af[1] = *(const bf16x8*)(Ab_ + ((MB) + 1) * 512); \
    af[2] = *(const bf16x8*)(Ab_ + ((MB) + 2) * 512); \
    af[3] = *(const bf16x8*)(Ab_ + ((MB) + 3) * 512); } while (0)

#define MFMA16(MB) do { \
    __builtin_amdgcn_s_setprio(1); \
    _Pragma("unroll") for (int m_ = 0; m_ < 4; m_++) \
        _Pragma("unroll") for (int n_ = 0; n_ < 4; n_++) \
            acc[(MB) + m_][n_] = __builtin_amdgcn_mfma_f32_16x16x32_bf16(af[m_], bfr[n_], acc[(MB) + m_][n_], 0, 0, 0); \
    __builtin_amdgcn_s_setprio(0); } while (0)

    bf16x8 af[4], bfr[4];

    STAGE_A(0, 0, 0);  STAGE_B(0, 0, 0);
    STAGE_A(0, 1, 32); STAGE_B(0, 1, 32);
    STAGE_A(1, 0, 64); STAGE_B(1, 0, 64);
    VMCNT(4);
    BARF();

    const int NIT = K >> 7;
    for (int it = 0; it < NIT - 1; ++it) {
        const int kb = it * 128;
        PH_AB(0, 0, 0); STAGE_A(1, 1, kb + 96);  BARF(); LGKM0(); MFMA16(0); BARF();
        PH_A (0, 0, 4); STAGE_B(1, 1, kb + 96);  BARF(); LGKM0(); MFMA16(4); BARF();
        PH_AB(0, 1, 0); STAGE_A(0, 0, kb + 128); BARF(); LGKM0(); MFMA16(0); BARF();
        PH_A (0, 1, 4); STAGE_B(0, 0, kb + 128); BARF(); LGKM0(); MFMA16(4); VMCNT(4); BARF();
        PH_AB(1, 0, 0); STAGE_A(0, 1, kb + 160); BARF(); LGKM0(); MFMA16(0); BARF();
        PH_A (1, 0, 4); STAGE_B(0, 1, kb + 160); BARF(); LGKM0(); MFMA16(4); BARF();
        PH_AB(1, 1, 0); STAGE_A(1, 0, kb + 192); BARF(); LGKM0(); MFMA16(0); BARF();
        PH_A (1, 1, 4); STAGE_B(1, 0, kb + 192); BARF(); LGKM0(); MFMA16(4); VMCNT(4); BARF();
    }
    {
        const int kb = (NIT - 1) * 128;
        PH_AB(0, 0, 0); STAGE_A(1, 1, kb + 96);  BARF(); LGKM0(); MFMA16(0); BARF();
        PH_A (0, 0, 4); STAGE_B(1, 1, kb + 96);  BARF(); LGKM0(); MFMA16(4); BARF();
        PH_AB(0, 1, 0);                          BARF(); LGKM0(); MFMA16(0); BARF();
        PH_A (0, 1, 4);                          BARF(); LGKM0(); MFMA16(4); VMCNT(0); BARF();
        PH_AB(1, 0, 0);                          BARF(); LGKM0(); MFMA16(0); BARF();
        PH_A (1, 0, 4);                          BARF(); LGKM0(); MFMA16(4); BARF();
        PH_AB(1, 1, 0);                          BARF(); LGKM0(); MFMA16(0); BARF();
        PH_A (1, 1, 4);                          BARF(); LGKM0(); MFMA16(4); BARF();
    }

#undef STAGE_A
#undef STAGE_B
#undef PH_AB
#undef PH_A
#undef MFMA16

    __syncthreads();
    for (int rr = 0; rr < 4; rr++) {
        if ((rr >> 1) == wm) {
            const int mb = (rr & 1) * 4;
            #pragma unroll
            for (int m = 0; m < 4; m++)
                #pragma unroll
                for (int n = 0; n < 4; n++)
                    #pragma unroll
                    for (int q = 0; q < 4; q++)
                        epi[(m * 16 + lq * 4 + q) * 260 + wn * 64 + n * 16 + lr] = acc[mb + m][n][q];
        }
        __syncthreads();
        #pragma unroll
        for (int k2 = 0; k2 < 8; k2++) {
            const int v = k2 * 512 + t;
            const int rl = v >> 6;
            const int c4 = (v & 63) * 4;
            float4 vec = *(float4*)&epi[rl * 260 + c4];
            const int grow = tileM + rr * 64 + rl;
            const int gcol = tileN + c4;
            *(float4*)&C[(size_t)grow * Nrows + gcol] = vec;
            if (vec.x > THRESH && grow < gcol)     dup[gcol]     = 1.f;
            if (vec.y > THRESH && grow < gcol + 1) dup[gcol + 1] = 1.f;
            if (vec.z > THRESH && grow < gcol + 2) dup[gcol + 2] = 1.f;
            if (vec.w > THRESH && grow < gcol + 3) dup[gcol + 3] = 1.f;
        }
        __syncthreads();
    }

    if (bm != bn) {
        for (int cc = 0; cc < 4; cc++) {
            if (wn == cc) {
                #pragma unroll
                for (int i2 = 0; i2 < 8; i2++)
                    #pragma unroll
                    for (int n = 0; n < 4; n++)
                        #pragma unroll
                        for (int q = 0; q < 4; q++)
                            epi[(n * 16 + lr) * 260 + wm * 128 + i2 * 16 + lq * 4 + q] = acc[i2][n][q];
            }
            __syncthreads();
            #pragma unroll
            for (int k2 = 0; k2 < 8; k2++) {
                const int v = k2 * 512 + t;
                const int rl = v >> 6;
                const int c4 = (v & 63) * 4;
                float4 vec = *(float4*)&epi[rl * 260 + c4];
                *(float4*)&C[(size_t)(tileN + cc * 64 + rl) * Nrows + tileM + c4] = vec;
            }
            __syncthreads();
        }
    }
}

// ---------------- launch ----------------

extern "C" void kernel_launch(void* const* d_in, const int* in_sizes, int n_in,
                              void* d_out, int out_size, void* d_ws, size_t ws_size,
                              hipStream_t stream) {
    const float* summaries = (const float*)d_in[0];
    const float* W1    = (const float*)d_in[1];
    const float* b1    = (const float*)d_in[2];
    const float* gamma = (const float*)d_in[3];
    const float* beta  = (const float*)d_in[4];
    const float* W2    = (const float*)d_in[5];
    const float* b2    = (const float*)d_in[6];

    float* sim = (float*)d_out;
    float* dup = sim + (size_t)NROWS * NROWS;

    char* ws = (char*)d_ws;
    float* hbuf = (float*)ws;                              // 32 MB: h, then enc
    short* xb   = (short*)(ws + (size_t)32 * 1024 * 1024); // 16 MB: Xb, then encb
    short* gbuf = (short*)(ws + (size_t)48 * 1024 * 1024); // 16 MB: g
    short* w1t  = (short*)(ws + (size_t)64 * 1024 * 1024); // 2 MB
    short* w2t  = (short*)(ws + (size_t)66 * 1024 * 1024); // 2 MB

    static int lds_init = 0;
    if (!lds_init) {
        hipFuncSetAttribute(reinterpret_cast<const void*>(gemm256_tri_k),
                            hipFuncAttributeMaxDynamicSharedMemorySize, 131072);
        hipFuncSetAttribute(reinterpret_cast<const void*>(gemm_dense256_k),
                            hipFuncAttributeMaxDynamicSharedMemorySize, 98304);
        lds_init = 1;
    }

    f32_to_bf16_k<<<dim3(NROWS * DIM / 1024), dim3(256), 0, stream>>>(summaries, xb, NROWS * DIM);
    transpose_to_bf16_k<<<dim3(32, 32), dim3(32, 8), 0, stream>>>(W1, w1t, DIM);
    transpose_to_bf16_k<<<dim3(32, 32), dim3(32, 8), 0, stream>>>(W2, w2t, DIM);
    zero_f32_k<<<dim3(32), dim3(256), 0, stream>>>(dup, NROWS);

    // h = X @ W1 + b1  (256 blocks, 1/CU, 4-phase pipelined)
    gemm_dense256_k<<<dim3(DIM / 256, NROWS / 128), dim3(512), 98304, stream>>>(
        xb, w1t, hbuf, b1, NROWS, DIM, DIM);
    // g = gelu(layernorm(h))
    ln_gelu_k<<<dim3(NROWS), dim3(256), 0, stream>>>(hbuf, gamma, beta, gbuf);
    // enc = g @ W2 + b2
    gemm_dense256_k<<<dim3(DIM / 256, NROWS / 128), dim3(512), 98304, stream>>>(
        gbuf, w2t, hbuf, b2, NROWS, DIM, DIM);
    // encb = normalize(enc) in bf16
    rownorm_bf16_k<<<dim3(NROWS), dim3(256), 0, stream>>>(hbuf, xb);
    // sim = encb @ encb^T : 256^2 8-phase triangular tiles + XCD swizzle
    const int NBT = NROWS / 256;
    gemm256_tri_k<<<dim3(NBT * (NBT + 1) / 2), dim3(512), 131072, stream>>>(
        xb, sim, dup, NROWS, DIM);
}

// Round 3
// 467.517 us; speedup vs baseline: 1.0596x; 1.0287x over previous
//
#include <hip/hip_runtime.h>
#include <hip/hip_bf16.h>

#define NROWS 8192
#define DIM   1024
#define THRESH 0.85f

typedef __attribute__((ext_vector_type(4))) float f32x4;
typedef __attribute__((ext_vector_type(8))) short bf16x8;

__device__ __forceinline__ short f2bf(float x) {
    union { float f; unsigned u; } c; c.f = x;
    unsigned r = c.u + 0x7FFFu + ((c.u >> 16) & 1u);
    return (short)(r >> 16);
}

__device__ __forceinline__ void async16(const void* g, void* l) {
    __builtin_amdgcn_global_load_lds(
        (const __attribute__((address_space(1))) void*)g,
        (__attribute__((address_space(3))) void*)l, 16, 0, 0);
}

// ---------------- merged prep kernel ----------------
// blocks [0, 8192):        summaries f32 -> bf16 (float4/short4)
// blocks [8192, 9216):     transpose W1 -> w1t bf16
// blocks [9216, 10240):    transpose W2 -> w2t bf16
// blocks [10240, 10272):   zero dup
__global__ __launch_bounds__(256) void prep_k(const float* __restrict__ summaries,
                                              short* __restrict__ xb,
                                              const float* __restrict__ W1,
                                              short* __restrict__ w1t,
                                              const float* __restrict__ W2,
                                              short* __restrict__ w2t,
                                              float* __restrict__ dup) {
    __shared__ float tile[32][33];
    const int b = blockIdx.x;
    const int t = threadIdx.x;
    if (b < 8192) {
        const int i = (b * 256 + t) * 4;
        float4 v = *(const float4*)(summaries + i);
        short4 o;
        o.x = f2bf(v.x); o.y = f2bf(v.y); o.z = f2bf(v.z); o.w = f2bf(v.w);
        *(short4*)(xb + i) = o;
    } else if (b < 10240) {
        const int tb = b - 8192;
        const float* in = (tb < 1024) ? W1 : W2;
        short* out = (tb < 1024) ? w1t : w2t;
        const int tid = tb & 1023;
        const int bx = (tid & 31) * 32, by = (tid >> 5) * 32;
        const int tx = t & 31, ty = t >> 5;        // 32 x 8
        for (int r = ty; r < 32; r += 8) tile[r][tx] = in[(size_t)(by + r) * DIM + bx + tx];
        __syncthreads();
        for (int r = ty; r < 32; r += 8) out[(size_t)(bx + r) * DIM + by + tx] = f2bf(tile[tx][r]);
    } else {
        const int i = (b - 10240) * 256 + t;
        if (i < NROWS) dup[i] = 0.f;
    }
}

// LayerNorm + exact GELU + bf16 cast, one row per block, float4 loads (G13).
__global__ __launch_bounds__(256) void ln_gelu_k(const float* __restrict__ h,
                                                 const float* __restrict__ gamma,
                                                 const float* __restrict__ beta,
                                                 short* __restrict__ g) {
    int row = blockIdx.x, t = threadIdx.x;
    const float* x = h + (size_t)row * DIM;
    float4 v4 = *(const float4*)(x + t * 4);
    float s = v4.x + v4.y + v4.z + v4.w;
    float ss = v4.x * v4.x + v4.y * v4.y + v4.z * v4.z + v4.w * v4.w;
    #pragma unroll
    for (int o = 32; o; o >>= 1) { s += __shfl_down(s, o, 64); ss += __shfl_down(ss, o, 64); }
    __shared__ float red[8];
    if ((t & 63) == 0) { red[(t >> 6) * 2] = s; red[(t >> 6) * 2 + 1] = ss; }
    __syncthreads();
    s  = red[0] + red[2] + red[4] + red[6];
    ss = red[1] + red[3] + red[5] + red[7];
    float mu = s * (1.0f / DIM);
    float var = ss * (1.0f / DIM) - mu * mu;
    float rstd = rsqrtf(var + 1e-5f);
    float4 g4 = *(const float4*)(gamma + t * 4);
    float4 b4 = *(const float4*)(beta + t * 4);
    float vv[4] = {v4.x, v4.y, v4.z, v4.w};
    float gg[4] = {g4.x, g4.y, g4.z, g4.w};
    float bb[4] = {b4.x, b4.y, b4.z, b4.w};
    short4 o;
    short* op = (short*)&o;
    #pragma unroll
    for (int i = 0; i < 4; i++) {
        float v = (vv[i] - mu) * rstd * gg[i] + bb[i];
        float ge = 0.5f * v * (1.0f + erff(v * 0.70710678118654752f));
        op[i] = f2bf(ge);
    }
    *(short4*)(g + (size_t)row * DIM + t * 4) = o;
}

// L2 row-normalize + bf16 cast, float4 loads.
__global__ __launch_bounds__(256) void rownorm_bf16_k(const float* __restrict__ enc,
                                                      short* __restrict__ out) {
    int row = blockIdx.x, t = threadIdx.x;
    const float* x = enc + (size_t)row * DIM;
    float4 v4 = *(const float4*)(x + t * 4);
    float ss = v4.x * v4.x + v4.y * v4.y + v4.z * v4.z + v4.w * v4.w;
    #pragma unroll
    for (int o = 32; o; o >>= 1) ss += __shfl_down(ss, o, 64);
    __shared__ float red[4];
    if ((t & 63) == 0) red[t >> 6] = ss;
    __syncthreads();
    ss = red[0] + red[1] + red[2] + red[3];
    float inv = 1.0f / fmaxf(sqrtf(ss), 1e-12f);
    short4 o;
    o.x = f2bf(v4.x * inv); o.y = f2bf(v4.y * inv);
    o.z = f2bf(v4.z * inv); o.w = f2bf(v4.w * inv);
    *(short4*)(out + (size_t)row * DIM + t * 4) = o;
}

#define BARF()   do { asm volatile("" ::: "memory"); __builtin_amdgcn_s_barrier(); asm volatile("" ::: "memory"); } while (0)
#define LGKM0()  asm volatile("s_waitcnt lgkmcnt(0)" ::: "memory")
#define VMCNT(n) asm volatile("s_waitcnt vmcnt(" #n ")" ::: "memory")

// ---------------- dense pipelined GEMM: C[M][N] = A[M][K] @ Bt[N][K]^T + bias ----------------
// BM=128, BN=256, BK=64 (two K-halves of 32). 512 threads = 8 waves (2M x 4N),
// 4-phase iteration over 2 K-tiles, counted vmcnt(6). Grid (4,64)=256 blocks = 1/CU.
__global__ __launch_bounds__(512, 2) void gemm_dense256_k(const short* __restrict__ A,
                                                          const short* __restrict__ Bt,
                                                          float* __restrict__ C,
                                                          const float* __restrict__ bias,
                                                          int M, int Nmat, int K) {
    extern __shared__ __align__(16) char smraw[];
    short* smA = (short*)smraw;        // 2*2*128*32 shorts = 32 KiB
    short* smB = smA + 16384;          // 2*2*256*32 shorts = 64 KiB
    float* epi = (float*)smraw;        // epilogue reuse: 32 x 260 f32

    const int tileN = blockIdx.x << 8;
    const int tileM = blockIdx.y << 7;

    const int t = threadIdx.x;
    const int wave = t >> 6;
    const int wm = wave >> 2, wn = wave & 3;   // 2M x 4N
    const int l = t & 63;
    const int lr = l & 15, lq = l >> 4;

    const int srow  = t >> 2;
    const int sslot = ((t & 3) ^ ((t >> 2) & 3)) * 8;
    const short* aS  = A  + (size_t)(tileM + srow) * K + sslot;
    const short* bS0 = Bt + (size_t)(tileN + srow) * K + sslot;
    const short* bS1 = bS0 + (size_t)128 * K;
    const int t8 = t * 8;

    const int swz  = (lq ^ (lr & 3)) * 8;
    const int aoff = (wm * 64 + lr) * 32 + swz;
    const int boff = (wn * 64 + lr) * 32 + swz;

    f32x4 acc[4][4];
    #pragma unroll
    for (int i = 0; i < 4; i++)
        #pragma unroll
        for (int j = 0; j < 4; j++) acc[i][j] = (f32x4){0.f, 0.f, 0.f, 0.f};

#define DSTAGE(DB, KH, KC) do { \
    short* da_ = smA + (DB) * 8192 + (KH) * 4096 + t8; \
    async16(aS + (KC), da_); \
    short* db_ = smB + (DB) * 16384 + (KH) * 8192 + t8; \
    async16(bS0 + (KC), db_); async16(bS1 + (KC), db_ + 4096); } while (0)

#define DPH(DB, KH) do { \
    const short* Ab_ = smA + (DB) * 8192 + (KH) * 4096 + aoff; \
    const short* Bb_ = smB + (DB) * 16384 + (KH) * 8192 + boff; \
    af[0] = *(const bf16x8*)(Ab_ + 0);    af[1] = *(const bf16x8*)(Ab_ + 512); \
    af[2] = *(const bf16x8*)(Ab_ + 1024); af[3] = *(const bf16x8*)(Ab_ + 1536); \
    bfr[0] = *(const bf16x8*)(Bb_ + 0);    bfr[1] = *(const bf16x8*)(Bb_ + 512); \
    bfr[2] = *(const bf16x8*)(Bb_ + 1024); bfr[3] = *(const bf16x8*)(Bb_ + 1536); } while (0)

#define DMFMA16() do { \
    __builtin_amdgcn_s_setprio(1); \
    _Pragma("unroll") for (int m_ = 0; m_ < 4; m_++) \
        _Pragma("unroll") for (int n_ = 0; n_ < 4; n_++) \
            acc[m_][n_] = __builtin_amdgcn_mfma_f32_16x16x32_bf16(af[m_], bfr[n_], acc[m_][n_], 0, 0, 0); \
    __builtin_amdgcn_s_setprio(0); } while (0)

    bf16x8 af[4], bfr[4];

    DSTAGE(0, 0, 0);
    DSTAGE(0, 1, 32);
    DSTAGE(1, 0, 64);
    VMCNT(6);
    BARF();

    const int NIT = K >> 7;
    for (int it = 0; it < NIT - 1; ++it) {
        const int kb = it * 128;
        DPH(0, 0); DSTAGE(1, 1, kb + 96);  BARF(); LGKM0(); DMFMA16(); VMCNT(6); BARF();
        DPH(0, 1); DSTAGE(0, 0, kb + 128); BARF(); LGKM0(); DMFMA16(); VMCNT(6); BARF();
        DPH(1, 0); DSTAGE(0, 1, kb + 160); BARF(); LGKM0(); DMFMA16(); VMCNT(6); BARF();
        DPH(1, 1); DSTAGE(1, 0, kb + 192); BARF(); LGKM0(); DMFMA16(); VMCNT(6); BARF();
    }
    {
        const int kb = (NIT - 1) * 128;
        DPH(0, 0); DSTAGE(1, 1, kb + 96);  BARF(); LGKM0(); DMFMA16(); VMCNT(6); BARF();
        DPH(0, 1);                         BARF(); LGKM0(); DMFMA16(); VMCNT(3); BARF();
        DPH(1, 0);                         BARF(); LGKM0(); DMFMA16(); VMCNT(0); BARF();
        DPH(1, 1);                         BARF(); LGKM0(); DMFMA16();           BARF();
    }

#undef DSTAGE
#undef DPH
#undef DMFMA16

    float bj[4];
    #pragma unroll
    for (int nb = 0; nb < 4; nb++) bj[nb] = bias[tileN + wn * 64 + nb * 16 + lr];
    __syncthreads();
    for (int rr = 0; rr < 4; rr++) {
        if (wm == (rr >> 1)) {
            #pragma unroll
            for (int h = 0; h < 2; h++) {
                const int mb = (rr & 1) * 2 + h;
                #pragma unroll
                for (int nb = 0; nb < 4; nb++)
                    #pragma unroll
                    for (int q = 0; q < 4; q++)
                        epi[(h * 16 + lq * 4 + q) * 260 + wn * 64 + nb * 16 + lr] = acc[mb][nb][q] + bj[nb];
            }
        }
        __syncthreads();
        #pragma unroll
        for (int k2 = 0; k2 < 4; k2++) {
            const int v = k2 * 512 + t;
            const int rl = v >> 6;
            const int c4 = (v & 63) * 4;
            float4 vec = *(float4*)&epi[rl * 260 + c4];
            *(float4*)&C[(size_t)(tileM + rr * 32 + rl) * Nmat + tileN + c4] = vec;
        }
        __syncthreads();
    }
}

// ---------------- 256x256 8-phase triangular sim GEMM (T1+T2+T3+T4+T5) ----------------
// Work items: 0..495 = off-diagonal pairs (r<c), 496..527 = diagonal tiles.
// blockIdx 0..511: XCD-chunked swizzle (chunk=64) over items 0..511;
// blockIdx 512..527 -> diag items 512..527, so the 3rd occupancy round's tail
// blocks are diagonal tiles (no mirror epilogue, ~12% shorter).
__global__ __launch_bounds__(512, 2) void gemm256_tri_k(const short* __restrict__ E,
                                                        float* __restrict__ C,
                                                        float* __restrict__ dup,
                                                        int Nrows, int K) {
    extern __shared__ __align__(16) char smraw[];
    short* smA = (short*)smraw;       // 2*2*256*32 shorts = 65536 B
    short* smB = smA + 32768;         // + 65536 B
    float* epi = (float*)smraw;       // epilogue reuse: 64 x 260 f32

    const int NBT = Nrows >> 8;       // 32
    int w = blockIdx.x;
    if (w < 512) w = (w & 7) * 64 + (w >> 3);
    int bm, bn;
    if (w >= 496) {
        bm = bn = w - 496;
    } else {
        int r = 0, off = 0;
        while (off + (NBT - 1 - r) <= w) { off += NBT - 1 - r; r++; }
        bm = r; bn = r + 1 + (w - off);
    }
    const int tileM = bm << 8, tileN = bn << 8;

    const int t = threadIdx.x;
    const int wave = t >> 6;
    const int wm = wave >> 2, wn = wave & 3;
    const int l = t & 63;
    const int lr = l & 15, lq = l >> 4;

    const int srow  = t >> 2;
    const int sslot = ((t & 3) ^ ((t >> 2) & 3)) * 8;
    const short* aS0 = E + (size_t)(tileM + srow) * K + sslot;
    const short* aS1 = aS0 + (size_t)128 * K;
    const short* bS0 = E + (size_t)(tileN + srow) * K + sslot;
    const short* bS1 = bS0 + (size_t)128 * K;
    const int ldst = t * 8;

    const int swz  = (lq ^ (lr & 3)) * 8;
    const int aoff = (wm * 128 + lr) * 32 + swz;
    const int boff = (wn * 64  + lr) * 32 + swz;

    f32x4 acc[8][4];
    #pragma unroll
    for (int i = 0; i < 8; i++)
        #pragma unroll
        for (int j = 0; j < 4; j++) acc[i][j] = (f32x4){0.f, 0.f, 0.f, 0.f};

#define STAGE_A(DB, KH, KC) do { \
    short* d_ = smA + (DB) * 16384 + (KH) * 8192 + ldst; \
    async16(aS0 + (KC), d_); async16(aS1 + (KC), d_ + 4096); } while (0)
#define STAGE_B(DB, KH, KC) do { \
    short* d_ = smB + (DB) * 16384 + (KH) * 8192 + ldst; \
    async16(bS0 + (KC), d_); async16(bS1 + (KC), d_ + 4096); } while (0)

#define PH_AB(DB, KS, MB) do { \
    const short* Ab_ = smA + (DB) * 16384 + (KS) * 8192 + aoff; \
    const short* Bb_ = smB + (DB) * 16384 + (KS) * 8192 + boff; \
    af[0] = *(const bf16x8*)(Ab_ + ((MB) + 0) * 512); \
    af[1] = *(const bf16x8*)(Ab_ + ((MB) + 1) * 512); \
    af[2] = *(const bf16x8*)(Ab_ + ((MB) + 2) * 512); \
    af[3] = *(const bf16x8*)(Ab_ + ((MB) + 3) * 512); \
    bfr[0] = *(const bf16x8*)(Bb_ + 0);    \
    bfr[1] = *(const bf16x8*)(Bb_ + 512);  \
    bfr[2] = *(const bf16x8*)(Bb_ + 1024); \
    bfr[3] = *(const bf16x8*)(Bb_ + 1536); } while (0)

#define PH_A(DB, KS, MB) do { \
    const short* Ab_ = smA + (DB) * 16384 + (KS) * 8192 + aoff; \
    af[0] = *(const bf16x8*)(Ab_ + ((MB) + 0) * 512); \
    af[1] = *(const bf16x8*)(Ab_ + ((MB) + 1) * 512); \
    af[2] = *(const bf16x8*)(Ab_ + ((MB) + 2) * 512); \
    af[3] = *(const bf16x8*)(Ab_ + ((MB) + 3) * 512); } while (0)

#define MFMA16(MB) do { \
    __builtin_amdgcn_s_setprio(1); \
    _Pragma("unroll") for (int m_ = 0; m_ < 4; m_++) \
        _Pragma("unroll") for (int n_ = 0; n_ < 4; n_++) \
            acc[(MB) + m_][n_] = __builtin_amdgcn_mfma_f32_16x16x32_bf16(af[m_], bfr[n_], acc[(MB) + m_][n_], 0, 0, 0); \
    __builtin_amdgcn_s_setprio(0); } while (0)

    bf16x8 af[4], bfr[4];

    STAGE_A(0, 0, 0);  STAGE_B(0, 0, 0);
    STAGE_A(0, 1, 32); STAGE_B(0, 1, 32);
    STAGE_A(1, 0, 64); STAGE_B(1, 0, 64);
    VMCNT(4);
    BARF();

    const int NIT = K >> 7;
    for (int it = 0; it < NIT - 1; ++it) {
        const int kb = it * 128;
        PH_AB(0, 0, 0); STAGE_A(1, 1, kb + 96);  BARF(); LGKM0(); MFMA16(0); BARF();
        PH_A (0, 0, 4); STAGE_B(1, 1, kb + 96);  BARF(); LGKM0(); MFMA16(4); BARF();
        PH_AB(0, 1, 0); STAGE_A(0, 0, kb + 128); BARF(); LGKM0(); MFMA16(0); BARF();
        PH_A (0, 1, 4); STAGE_B(0, 0, kb + 128); BARF(); LGKM0(); MFMA16(4); VMCNT(4); BARF();
        PH_AB(1, 0, 0); STAGE_A(0, 1, kb + 160); BARF(); LGKM0(); MFMA16(0); BARF();
        PH_A (1, 0, 4); STAGE_B(0, 1, kb + 160); BARF(); LGKM0(); MFMA16(4); BARF();
        PH_AB(1, 1, 0); STAGE_A(1, 0, kb + 192); BARF(); LGKM0(); MFMA16(0); BARF();
        PH_A (1, 1, 4); STAGE_B(1, 0, kb + 192); BARF(); LGKM0(); MFMA16(4); VMCNT(4); BARF();
    }
    {
        const int kb = (NIT - 1) * 128;
        PH_AB(0, 0, 0); STAGE_A(1, 1, kb + 96);  BARF(); LGKM0(); MFMA16(0); BARF();
        PH_A (0, 0, 4); STAGE_B(1, 1, kb + 96);  BARF(); LGKM0(); MFMA16(4); BARF();
        PH_AB(0, 1, 0);                          BARF(); LGKM0(); MFMA16(0); BARF();
        PH_A (0, 1, 4);                          BARF(); LGKM0(); MFMA16(4); VMCNT(0); BARF();
        PH_AB(1, 0, 0);                          BARF(); LGKM0(); MFMA16(0); BARF();
        PH_A (1, 0, 4);                          BARF(); LGKM0(); MFMA16(4); BARF();
        PH_AB(1, 1, 0);                          BARF(); LGKM0(); MFMA16(0); BARF();
        PH_A (1, 1, 4);                          BARF(); LGKM0(); MFMA16(4); BARF();
    }

#undef STAGE_A
#undef STAGE_B
#undef PH_AB
#undef PH_A
#undef MFMA16

    __syncthreads();
    for (int rr = 0; rr < 4; rr++) {
        if ((rr >> 1) == wm) {
            const int mb = (rr & 1) * 4;
            #pragma unroll
            for (int m = 0; m < 4; m++)
                #pragma unroll
                for (int n = 0; n < 4; n++)
                    #pragma unroll
                    for (int q = 0; q < 4; q++)
                        epi[(m * 16 + lq * 4 + q) * 260 + wn * 64 + n * 16 + lr] = acc[mb + m][n][q];
        }
        __syncthreads();
        #pragma unroll
        for (int k2 = 0; k2 < 8; k2++) {
            const int v = k2 * 512 + t;
            const int rl = v >> 6;
            const int c4 = (v & 63) * 4;
            float4 vec = *(float4*)&epi[rl * 260 + c4];
            const int grow = tileM + rr * 64 + rl;
            const int gcol = tileN + c4;
            *(float4*)&C[(size_t)grow * Nrows + gcol] = vec;
            if (vec.x > THRESH && grow < gcol)     dup[gcol]     = 1.f;
            if (vec.y > THRESH && grow < gcol + 1) dup[gcol + 1] = 1.f;
            if (vec.z > THRESH && grow < gcol + 2) dup[gcol + 2] = 1.f;
            if (vec.w > THRESH && grow < gcol + 3) dup[gcol + 3] = 1.f;
        }
        __syncthreads();
    }

    if (bm != bn) {
        for (int cc = 0; cc < 4; cc++) {
            if (wn == cc) {
                #pragma unroll
                for (int i2 = 0; i2 < 8; i2++)
                    #pragma unroll
                    for (int n = 0; n < 4; n++)
                        #pragma unroll
                        for (int q = 0; q < 4; q++)
                            epi[(n * 16 + lr) * 260 + wm * 128 + i2 * 16 + lq * 4 + q] = acc[i2][n][q];
            }
            __syncthreads();
            #pragma unroll
            for (int k2 = 0; k2 < 8; k2++) {
                const int v = k2 * 512 + t;
                const int rl = v >> 6;
                const int c4 = (v & 63) * 4;
                float4 vec = *(float4*)&epi[rl * 260 + c4];
                *(float4*)&C[(size_t)(tileN + cc * 64 + rl) * Nrows + tileM + c4] = vec;
            }
            __syncthreads();
        }
    }
}

// ---------------- launch ----------------

extern "C" void kernel_launch(void* const* d_in, const int* in_sizes, int n_in,
                              void* d_out, int out_size, void* d_ws, size_t ws_size,
                              hipStream_t stream) {
    const float* summaries = (const float*)d_in[0];
    const float* W1    = (const float*)d_in[1];
    const float* b1    = (const float*)d_in[2];
    const float* gamma = (const float*)d_in[3];
    const float* beta  = (const float*)d_in[4];
    const float* W2    = (const float*)d_in[5];
    const float* b2    = (const float*)d_in[6];

    float* sim = (float*)d_out;
    float* dup = sim + (size_t)NROWS * NROWS;

    char* ws = (char*)d_ws;
    float* hbuf = (float*)ws;                              // 32 MB: h, then enc
    short* xb   = (short*)(ws + (size_t)32 * 1024 * 1024); // 16 MB: Xb, then encb
    short* gbuf = (short*)(ws + (size_t)48 * 1024 * 1024); // 16 MB: g
    short* w1t  = (short*)(ws + (size_t)64 * 1024 * 1024); // 2 MB
    short* w2t  = (short*)(ws + (size_t)66 * 1024 * 1024); // 2 MB

    static int lds_init = 0;
    if (!lds_init) {
        hipFuncSetAttribute(reinterpret_cast<const void*>(gemm256_tri_k),
                            hipFuncAttributeMaxDynamicSharedMemorySize, 131072);
        hipFuncSetAttribute(reinterpret_cast<const void*>(gemm_dense256_k),
                            hipFuncAttributeMaxDynamicSharedMemorySize, 98304);
        lds_init = 1;
    }

    // merged prep: convert + both transposes + dup zero (one dispatch)
    prep_k<<<dim3(10272), dim3(256), 0, stream>>>(summaries, xb, W1, w1t, W2, w2t, dup);

    // h = X @ W1 + b1  (256 blocks, 1/CU, 4-phase pipelined)
    gemm_dense256_k<<<dim3(DIM / 256, NROWS / 128), dim3(512), 98304, stream>>>(
        xb, w1t, hbuf, b1, NROWS, DIM, DIM);
    // g = gelu(layernorm(h))
    ln_gelu_k<<<dim3(NROWS), dim3(256), 0, stream>>>(hbuf, gamma, beta, gbuf);
    // enc = g @ W2 + b2
    gemm_dense256_k<<<dim3(DIM / 256, NROWS / 128), dim3(512), 98304, stream>>>(
        gbuf, w2t, hbuf, b2, NROWS, DIM, DIM);
    // encb = normalize(enc) in bf16
    rownorm_bf16_k<<<dim3(NROWS), dim3(256), 0, stream>>>(hbuf, xb);
    // sim = encb @ encb^T : 256^2 8-phase triangular tiles, diag-last grid
    const int NBT = NROWS / 256;
    gemm256_tri_k<<<dim3(NBT * (NBT + 1) / 2), dim3(512), 131072, stream>>>(
        xb, sim, dup, NROWS, DIM);
}

// Round 4
// 463.573 us; speedup vs baseline: 1.0686x; 1.0085x over previous
//
#include <hip/hip_runtime.h>
#include <hip/hip_bf16.h>

#define NROWS 8192
#define DIM   1024
#define THRESH 0.85f

typedef __attribute__((ext_vector_type(4))) float f32x4;
typedef __attribute__((ext_vector_type(8))) short bf16x8;

__device__ __forceinline__ short f2bf(float x) {
    union { float f; unsigned u; } c; c.f = x;
    unsigned r = c.u + 0x7FFFu + ((c.u >> 16) & 1u);
    return (short)(r >> 16);
}

__device__ __forceinline__ void async16(const void* g, void* l) {
    __builtin_amdgcn_global_load_lds(
        (const __attribute__((address_space(1))) void*)g,
        (__attribute__((address_space(3))) void*)l, 16, 0, 0);
}

// ---------------- merged prep kernel ----------------
// blocks [0, 8192):        summaries f32 -> bf16 (float4/short4)
// blocks [8192, 9216):     transpose W1 -> w1t bf16
// blocks [9216, 10240):    transpose W2 -> w2t bf16
// blocks [10240, 10272):   zero dup
__global__ __launch_bounds__(256) void prep_k(const float* __restrict__ summaries,
                                              short* __restrict__ xb,
                                              const float* __restrict__ W1,
                                              short* __restrict__ w1t,
                                              const float* __restrict__ W2,
                                              short* __restrict__ w2t,
                                              float* __restrict__ dup) {
    __shared__ float tile[32][33];
    const int b = blockIdx.x;
    const int t = threadIdx.x;
    if (b < 8192) {
        const int i = (b * 256 + t) * 4;
        float4 v = *(const float4*)(summaries + i);
        short4 o;
        o.x = f2bf(v.x); o.y = f2bf(v.y); o.z = f2bf(v.z); o.w = f2bf(v.w);
        *(short4*)(xb + i) = o;
    } else if (b < 10240) {
        const int tb = b - 8192;
        const float* in = (tb < 1024) ? W1 : W2;
        short* out = (tb < 1024) ? w1t : w2t;
        const int tid = tb & 1023;
        const int bx = (tid & 31) * 32, by = (tid >> 5) * 32;
        const int tx = t & 31, ty = t >> 5;        // 32 x 8
        for (int r = ty; r < 32; r += 8) tile[r][tx] = in[(size_t)(by + r) * DIM + bx + tx];
        __syncthreads();
        for (int r = ty; r < 32; r += 8) out[(size_t)(bx + r) * DIM + by + tx] = f2bf(tile[tx][r]);
    } else {
        const int i = (b - 10240) * 256 + t;
        if (i < NROWS) dup[i] = 0.f;
    }
}

// LayerNorm + exact GELU + bf16 cast, one row per block, float4 loads (G13).
__global__ __launch_bounds__(256) void ln_gelu_k(const float* __restrict__ h,
                                                 const float* __restrict__ gamma,
                                                 const float* __restrict__ beta,
                                                 short* __restrict__ g) {
    int row = blockIdx.x, t = threadIdx.x;
    const float* x = h + (size_t)row * DIM;
    float4 v4 = *(const float4*)(x + t * 4);
    float s = v4.x + v4.y + v4.z + v4.w;
    float ss = v4.x * v4.x + v4.y * v4.y + v4.z * v4.z + v4.w * v4.w;
    #pragma unroll
    for (int o = 32; o; o >>= 1) { s += __shfl_down(s, o, 64); ss += __shfl_down(ss, o, 64); }
    __shared__ float red[8];
    if ((t & 63) == 0) { red[(t >> 6) * 2] = s; red[(t >> 6) * 2 + 1] = ss; }
    __syncthreads();
    s  = red[0] + red[2] + red[4] + red[6];
    ss = red[1] + red[3] + red[5] + red[7];
    float mu = s * (1.0f / DIM);
    float var = ss * (1.0f / DIM) - mu * mu;
    float rstd = rsqrtf(var + 1e-5f);
    float4 g4 = *(const float4*)(gamma + t * 4);
    float4 b4 = *(const float4*)(beta + t * 4);
    float vv[4] = {v4.x, v4.y, v4.z, v4.w};
    float gg[4] = {g4.x, g4.y, g4.z, g4.w};
    float bb[4] = {b4.x, b4.y, b4.z, b4.w};
    short4 o;
    short* op = (short*)&o;
    #pragma unroll
    for (int i = 0; i < 4; i++) {
        float v = (vv[i] - mu) * rstd * gg[i] + bb[i];
        float ge = 0.5f * v * (1.0f + erff(v * 0.70710678118654752f));
        op[i] = f2bf(ge);
    }
    *(short4*)(g + (size_t)row * DIM + t * 4) = o;
}

// L2 row-normalize + bf16 cast, float4 loads.
__global__ __launch_bounds__(256) void rownorm_bf16_k(const float* __restrict__ enc,
                                                      short* __restrict__ out) {
    int row = blockIdx.x, t = threadIdx.x;
    const float* x = enc + (size_t)row * DIM;
    float4 v4 = *(const float4*)(x + t * 4);
    float ss = v4.x * v4.x + v4.y * v4.y + v4.z * v4.z + v4.w * v4.w;
    #pragma unroll
    for (int o = 32; o; o >>= 1) ss += __shfl_down(ss, o, 64);
    __shared__ float red[4];
    if ((t & 63) == 0) red[t >> 6] = ss;
    __syncthreads();
    ss = red[0] + red[1] + red[2] + red[3];
    float inv = 1.0f / fmaxf(sqrtf(ss), 1e-12f);
    short4 o;
    o.x = f2bf(v4.x * inv); o.y = f2bf(v4.y * inv);
    o.z = f2bf(v4.z * inv); o.w = f2bf(v4.w * inv);
    *(short4*)(out + (size_t)row * DIM + t * 4) = o;
}

#define BARF()   do { asm volatile("" ::: "memory"); __builtin_amdgcn_s_barrier(); asm volatile("" ::: "memory"); } while (0)
#define LGKM0()  asm volatile("s_waitcnt lgkmcnt(0)" ::: "memory")
#define VMCNT(n) asm volatile("s_waitcnt vmcnt(" #n ")" ::: "memory")

// ---------------- dense pipelined GEMM: C[M][N] = A[M][K] @ Bt[N][K]^T + bias ----------------
// BM=128, BN=256, BK=64 (two K-halves of 32). 512 threads = 8 waves (2M x 4N),
// 4-phase iteration over 2 K-tiles, counted vmcnt(6). Grid (4,64)=256 blocks = 1/CU.
// Swizzle (R4): slot = c ^ ((row>>1)&3) -> frag ds_read_b128 conflicts are 2-way (free)
// instead of 4-way (1.58x). Staging source pre-swizzled with the same XOR.
__global__ __launch_bounds__(512, 2) void gemm_dense256_k(const short* __restrict__ A,
                                                          const short* __restrict__ Bt,
                                                          float* __restrict__ C,
                                                          const float* __restrict__ bias,
                                                          int M, int Nmat, int K) {
    extern __shared__ __align__(16) char smraw[];
    short* smA = (short*)smraw;        // 2*2*128*32 shorts = 32 KiB
    short* smB = smA + 16384;          // 2*2*256*32 shorts = 64 KiB
    float* epi = (float*)smraw;        // epilogue reuse: 32 x 260 f32

    const int tileN = blockIdx.x << 8;
    const int tileM = blockIdx.y << 7;

    const int t = threadIdx.x;
    const int wave = t >> 6;
    const int wm = wave >> 2, wn = wave & 3;   // 2M x 4N
    const int l = t & 63;
    const int lr = l & 15, lq = l >> 4;

    const int srow  = t >> 2;
    const int sslot = ((t & 3) ^ ((t >> 3) & 3)) * 8;   // c = s ^ ((row>>1)&3), row = t>>2
    const short* aS  = A  + (size_t)(tileM + srow) * K + sslot;
    const short* bS0 = Bt + (size_t)(tileN + srow) * K + sslot;
    const short* bS1 = bS0 + (size_t)128 * K;
    const int t8 = t * 8;

    const int swz  = (lq ^ ((lr >> 1) & 3)) * 8;        // read slot for content lq at row lr
    const int aoff = (wm * 64 + lr) * 32 + swz;
    const int boff = (wn * 64 + lr) * 32 + swz;

    f32x4 acc[4][4];
    #pragma unroll
    for (int i = 0; i < 4; i++)
        #pragma unroll
        for (int j = 0; j < 4; j++) acc[i][j] = (f32x4){0.f, 0.f, 0.f, 0.f};

#define DSTAGE(DB, KH, KC) do { \
    short* da_ = smA + (DB) * 8192 + (KH) * 4096 + t8; \
    async16(aS + (KC), da_); \
    short* db_ = smB + (DB) * 16384 + (KH) * 8192 + t8; \
    async16(bS0 + (KC), db_); async16(bS1 + (KC), db_ + 4096); } while (0)

#define DPH(DB, KH) do { \
    const short* Ab_ = smA + (DB) * 8192 + (KH) * 4096 + aoff; \
    const short* Bb_ = smB + (DB) * 16384 + (KH) * 8192 + boff; \
    af[0] = *(const bf16x8*)(Ab_ + 0);    af[1] = *(const bf16x8*)(Ab_ + 512); \
    af[2] = *(const bf16x8*)(Ab_ + 1024); af[3] = *(const bf16x8*)(Ab_ + 1536); \
    bfr[0] = *(const bf16x8*)(Bb_ + 0);    bfr[1] = *(const bf16x8*)(Bb_ + 512); \
    bfr[2] = *(const bf16x8*)(Bb_ + 1024); bfr[3] = *(const bf16x8*)(Bb_ + 1536); } while (0)

#define DMFMA16() do { \
    __builtin_amdgcn_s_setprio(1); \
    _Pragma("unroll") for (int m_ = 0; m_ < 4; m_++) \
        _Pragma("unroll") for (int n_ = 0; n_ < 4; n_++) \
            acc[m_][n_] = __builtin_amdgcn_mfma_f32_16x16x32_bf16(af[m_], bfr[n_], acc[m_][n_], 0, 0, 0); \
    __builtin_amdgcn_s_setprio(0); } while (0)

    bf16x8 af[4], bfr[4];

    DSTAGE(0, 0, 0);
    DSTAGE(0, 1, 32);
    DSTAGE(1, 0, 64);
    VMCNT(6);
    BARF();

    const int NIT = K >> 7;
    for (int it = 0; it < NIT - 1; ++it) {
        const int kb = it * 128;
        DPH(0, 0); DSTAGE(1, 1, kb + 96);  BARF(); LGKM0(); DMFMA16(); VMCNT(6); BARF();
        DPH(0, 1); DSTAGE(0, 0, kb + 128); BARF(); LGKM0(); DMFMA16(); VMCNT(6); BARF();
        DPH(1, 0); DSTAGE(0, 1, kb + 160); BARF(); LGKM0(); DMFMA16(); VMCNT(6); BARF();
        DPH(1, 1); DSTAGE(1, 0, kb + 192); BARF(); LGKM0(); DMFMA16(); VMCNT(6); BARF();
    }
    {
        const int kb = (NIT - 1) * 128;
        DPH(0, 0); DSTAGE(1, 1, kb + 96);  BARF(); LGKM0(); DMFMA16(); VMCNT(6); BARF();
        DPH(0, 1);                         BARF(); LGKM0(); DMFMA16(); VMCNT(3); BARF();
        DPH(1, 0);                         BARF(); LGKM0(); DMFMA16(); VMCNT(0); BARF();
        DPH(1, 1);                         BARF(); LGKM0(); DMFMA16();           BARF();
    }

#undef DSTAGE
#undef DPH
#undef DMFMA16

    float bj[4];
    #pragma unroll
    for (int nb = 0; nb < 4; nb++) bj[nb] = bias[tileN + wn * 64 + nb * 16 + lr];
    __syncthreads();
    for (int rr = 0; rr < 4; rr++) {
        if (wm == (rr >> 1)) {
            #pragma unroll
            for (int h = 0; h < 2; h++) {
                const int mb = (rr & 1) * 2 + h;
                #pragma unroll
                for (int nb = 0; nb < 4; nb++)
                    #pragma unroll
                    for (int q = 0; q < 4; q++)
                        epi[(h * 16 + lq * 4 + q) * 260 + wn * 64 + nb * 16 + lr] = acc[mb][nb][q] + bj[nb];
            }
        }
        __syncthreads();
        #pragma unroll
        for (int k2 = 0; k2 < 4; k2++) {
            const int v = k2 * 512 + t;
            const int rl = v >> 6;
            const int c4 = (v & 63) * 4;
            float4 vec = *(float4*)&epi[rl * 260 + c4];
            *(float4*)&C[(size_t)(tileM + rr * 32 + rl) * Nmat + tileN + c4] = vec;
        }
        __syncthreads();
    }
}

// ---------------- 256x256 8-phase triangular sim GEMM (T1+T2+T3+T4+T5) ----------------
// Work items: 0..495 = off-diagonal pairs (r<c), 496..527 = diagonal tiles.
// blockIdx 0..511: XCD-chunked swizzle (chunk=64) over items 0..511;
// blockIdx 512..527 -> diag items (tail round = short diagonal tiles).
// Swizzle (R4): slot = c ^ ((row>>1)&3) -> 2-way (free) ds_read conflicts.
__global__ __launch_bounds__(512, 2) void gemm256_tri_k(const short* __restrict__ E,
                                                        float* __restrict__ C,
                                                        float* __restrict__ dup,
                                                        int Nrows, int K) {
    extern __shared__ __align__(16) char smraw[];
    short* smA = (short*)smraw;       // 2*2*256*32 shorts = 65536 B
    short* smB = smA + 32768;         // + 65536 B
    float* epi = (float*)smraw;       // epilogue reuse: 64 x 260 f32

    const int NBT = Nrows >> 8;       // 32
    int w = blockIdx.x;
    if (w < 512) w = (w & 7) * 64 + (w >> 3);
    int bm, bn;
    if (w >= 496) {
        bm = bn = w - 496;
    } else {
        int r = 0, off = 0;
        while (off + (NBT - 1 - r) <= w) { off += NBT - 1 - r; r++; }
        bm = r; bn = r + 1 + (w - off);
    }
    const int tileM = bm << 8, tileN = bn << 8;

    const int t = threadIdx.x;
    const int wave = t >> 6;
    const int wm = wave >> 2, wn = wave & 3;
    const int l = t & 63;
    const int lr = l & 15, lq = l >> 4;

    const int srow  = t >> 2;
    const int sslot = ((t & 3) ^ ((t >> 3) & 3)) * 8;   // c = s ^ ((row>>1)&3)
    const short* aS0 = E + (size_t)(tileM + srow) * K + sslot;
    const short* aS1 = aS0 + (size_t)128 * K;
    const short* bS0 = E + (size_t)(tileN + srow) * K + sslot;
    const short* bS1 = bS0 + (size_t)128 * K;
    const int ldst = t * 8;

    const int swz  = (lq ^ ((lr >> 1) & 3)) * 8;
    const int aoff = (wm * 128 + lr) * 32 + swz;
    const int boff = (wn * 64  + lr) * 32 + swz;

    f32x4 acc[8][4];
    #pragma unroll
    for (int i = 0; i < 8; i++)
        #pragma unroll
        for (int j = 0; j < 4; j++) acc[i][j] = (f32x4){0.f, 0.f, 0.f, 0.f};

#define STAGE_A(DB, KH, KC) do { \
    short* d_ = smA + (DB) * 16384 + (KH) * 8192 + ldst; \
    async16(aS0 + (KC), d_); async16(aS1 + (KC), d_ + 4096); } while (0)
#define STAGE_B(DB, KH, KC) do { \
    short* d_ = smB + (DB) * 16384 + (KH) * 8192 + ldst; \
    async16(bS0 + (KC), d_); async16(bS1 + (KC), d_ + 4096); } while (0)

#define PH_AB(DB, KS, MB) do { \
    const short* Ab_ = smA + (DB) * 16384 + (KS) * 8192 + aoff; \
    const short* Bb_ = smB + (DB) * 16384 + (KS) * 8192 + boff; \
    af[0] = *(const bf16x8*)(Ab_ + ((MB) + 0) * 512); \
    af[1] = *(const bf16x8*)(Ab_ + ((MB) + 1) * 512); \
    af[2] = *(const bf16x8*)(Ab_ + ((MB) + 2) * 512); \
    af[3] = *(const bf16x8*)(Ab_ + ((MB) + 3) * 512); \
    bfr[0] = *(const bf16x8*)(Bb_ + 0);    \
    bfr[1] = *(const bf16x8*)(Bb_ + 512);  \
    bfr[2] = *(const bf16x8*)(Bb_ + 1024); \
    bfr[3] = *(const bf16x8*)(Bb_ + 1536); } while (0)

#define PH_A(DB, KS, MB) do { \
    const short* Ab_ = smA + (DB) * 16384 + (KS) * 8192 + aoff; \
    af[0] = *(const bf16x8*)(Ab_ + ((MB) + 0) * 512); \
    af[1] = *(const bf16x8*)(Ab_ + ((MB) + 1) * 512); \
    af[2] = *(const bf16x8*)(Ab_ + ((MB) + 2) * 512); \
    af[3] = *(const bf16x8*)(Ab_ + ((MB) + 3) * 512); } while (0)

#define MFMA16(MB) do { \
    __builtin_amdgcn_s_setprio(1); \
    _Pragma("unroll") for (int m_ = 0; m_ < 4; m_++) \
        _Pragma("unroll") for (int n_ = 0; n_ < 4; n_++) \
            acc[(MB) + m_][n_] = __builtin_amdgcn_mfma_f32_16x16x32_bf16(af[m_], bfr[n_], acc[(MB) + m_][n_], 0, 0, 0); \
    __builtin_amdgcn_s_setprio(0); } while (0)

    bf16x8 af[4], bfr[4];

    STAGE_A(0, 0, 0);  STAGE_B(0, 0, 0);
    STAGE_A(0, 1, 32); STAGE_B(0, 1, 32);
    STAGE_A(1, 0, 64); STAGE_B(1, 0, 64);
    VMCNT(4);
    BARF();

    const int NIT = K >> 7;
    for (int it = 0; it < NIT - 1; ++it) {
        const int kb = it * 128;
        PH_AB(0, 0, 0); STAGE_A(1, 1, kb + 96);  BARF(); LGKM0(); MFMA16(0); BARF();
        PH_A (0, 0, 4); STAGE_B(1, 1, kb + 96);  BARF(); LGKM0(); MFMA16(4); BARF();
        PH_AB(0, 1, 0); STAGE_A(0, 0, kb + 128); BARF(); LGKM0(); MFMA16(0); BARF();
        PH_A (0, 1, 4); STAGE_B(0, 0, kb + 128); BARF(); LGKM0(); MFMA16(4); VMCNT(4); BARF();
        PH_AB(1, 0, 0); STAGE_A(0, 1, kb + 160); BARF(); LGKM0(); MFMA16(0); BARF();
        PH_A (1, 0, 4); STAGE_B(0, 1, kb + 160); BARF(); LGKM0(); MFMA16(4); BARF();
        PH_AB(1, 1, 0); STAGE_A(1, 0, kb + 192); BARF(); LGKM0(); MFMA16(0); BARF();
        PH_A (1, 1, 4); STAGE_B(1, 0, kb + 192); BARF(); LGKM0(); MFMA16(4); VMCNT(4); BARF();
    }
    {
        const int kb = (NIT - 1) * 128;
        PH_AB(0, 0, 0); STAGE_A(1, 1, kb + 96);  BARF(); LGKM0(); MFMA16(0); BARF();
        PH_A (0, 0, 4); STAGE_B(1, 1, kb + 96);  BARF(); LGKM0(); MFMA16(4); BARF();
        PH_AB(0, 1, 0);                          BARF(); LGKM0(); MFMA16(0); BARF();
        PH_A (0, 1, 4);                          BARF(); LGKM0(); MFMA16(4); VMCNT(0); BARF();
        PH_AB(1, 0, 0);                          BARF(); LGKM0(); MFMA16(0); BARF();
        PH_A (1, 0, 4);                          BARF(); LGKM0(); MFMA16(4); BARF();
        PH_AB(1, 1, 0);                          BARF(); LGKM0(); MFMA16(0); BARF();
        PH_A (1, 1, 4);                          BARF(); LGKM0(); MFMA16(4); BARF();
    }

#undef STAGE_A
#undef STAGE_B
#undef PH_AB
#undef PH_A
#undef MFMA16

    __syncthreads();
    for (int rr = 0; rr < 4; rr++) {
        if ((rr >> 1) == wm) {
            const int mb = (rr & 1) * 4;
            #pragma unroll
            for (int m = 0; m < 4; m++)
                #pragma unroll
                for (int n = 0; n < 4; n++)
                    #pragma unroll
                    for (int q = 0; q < 4; q++)
                        epi[(m * 16 + lq * 4 + q) * 260 + wn * 64 + n * 16 + lr] = acc[mb + m][n][q];
        }
        __syncthreads();
        #pragma unroll
        for (int k2 = 0; k2 < 8; k2++) {
            const int v = k2 * 512 + t;
            const int rl = v >> 6;
            const int c4 = (v & 63) * 4;
            float4 vec = *(float4*)&epi[rl * 260 + c4];
            const int grow = tileM + rr * 64 + rl;
            const int gcol = tileN + c4;
            *(float4*)&C[(size_t)grow * Nrows + gcol] = vec;
            if (vec.x > THRESH && grow < gcol)     dup[gcol]     = 1.f;
            if (vec.y > THRESH && grow < gcol + 1) dup[gcol + 1] = 1.f;
            if (vec.z > THRESH && grow < gcol + 2) dup[gcol + 2] = 1.f;
            if (vec.w > THRESH && grow < gcol + 3) dup[gcol + 3] = 1.f;
        }
        __syncthreads();
    }

    if (bm != bn) {
        for (int cc = 0; cc < 4; cc++) {
            if (wn == cc) {
                #pragma unroll
                for (int i2 = 0; i2 < 8; i2++)
                    #pragma unroll
                    for (int n = 0; n < 4; n++)
                        #pragma unroll
                        for (int q = 0; q < 4; q++)
                            epi[(n * 16 + lr) * 260 + wm * 128 + i2 * 16 + lq * 4 + q] = acc[i2][n][q];
            }
            __syncthreads();
            #pragma unroll
            for (int k2 = 0; k2 < 8; k2++) {
                const int v = k2 * 512 + t;
                const int rl = v >> 6;
                const int c4 = (v & 63) * 4;
                float4 vec = *(float4*)&epi[rl * 260 + c4];
                *(float4*)&C[(size_t)(tileN + cc * 64 + rl) * Nrows + tileM + c4] = vec;
            }
            __syncthreads();
        }
    }
}

// ---------------- launch ----------------

extern "C" void kernel_launch(void* const* d_in, const int* in_sizes, int n_in,
                              void* d_out, int out_size, void* d_ws, size_t ws_size,
                              hipStream_t stream) {
    const float* summaries = (const float*)d_in[0];
    const float* W1    = (const float*)d_in[1];
    const float* b1    = (const float*)d_in[2];
    const float* gamma = (const float*)d_in[3];
    const float* beta  = (const float*)d_in[4];
    const float* W2    = (const float*)d_in[5];
    const float* b2    = (const float*)d_in[6];

    float* sim = (float*)d_out;
    float* dup = sim + (size_t)NROWS * NROWS;

    char* ws = (char*)d_ws;
    float* hbuf = (float*)ws;                              // 32 MB: h, then enc
    short* xb   = (short*)(ws + (size_t)32 * 1024 * 1024); // 16 MB: Xb, then encb
    short* gbuf = (short*)(ws + (size_t)48 * 1024 * 1024); // 16 MB: g
    short* w1t  = (short*)(ws + (size_t)64 * 1024 * 1024); // 2 MB
    short* w2t  = (short*)(ws + (size_t)66 * 1024 * 1024); // 2 MB

    static int lds_init = 0;
    if (!lds_init) {
        hipFuncSetAttribute(reinterpret_cast<const void*>(gemm256_tri_k),
                            hipFuncAttributeMaxDynamicSharedMemorySize, 131072);
        hipFuncSetAttribute(reinterpret_cast<const void*>(gemm_dense256_k),
                            hipFuncAttributeMaxDynamicSharedMemorySize, 98304);
        lds_init = 1;
    }

    // merged prep: convert + both transposes + dup zero (one dispatch)
    prep_k<<<dim3(10272), dim3(256), 0, stream>>>(summaries, xb, W1, w1t, W2, w2t, dup);

    // h = X @ W1 + b1  (256 blocks, 1/CU, 4-phase pipelined)
    gemm_dense256_k<<<dim3(DIM / 256, NROWS / 128), dim3(512), 98304, stream>>>(
        xb, w1t, hbuf, b1, NROWS, DIM, DIM);
    // g = gelu(layernorm(h))
    ln_gelu_k<<<dim3(NROWS), dim3(256), 0, stream>>>(hbuf, gamma, beta, gbuf);
    // enc = g @ W2 + b2
    gemm_dense256_k<<<dim3(DIM / 256, NROWS / 128), dim3(512), 98304, stream>>>(
        gbuf, w2t, hbuf, b2, NROWS, DIM, DIM);
    // encb = normalize(enc) in bf16
    rownorm_bf16_k<<<dim3(NROWS), dim3(256), 0, stream>>>(hbuf, xb);
    // sim = encb @ encb^T : 256^2 8-phase triangular tiles, diag-last grid
    const int NBT = NROWS / 256;
    gemm256_tri_k<<<dim3(NBT * (NBT + 1) / 2), dim3(512), 131072, stream>>>(
        xb, sim, dup, NROWS, DIM);
}

// Round 5
// 449.440 us; speedup vs baseline: 1.1022x; 1.0314x over previous
//
#include <hip/hip_runtime.h>
#include <hip/hip_bf16.h>

#define NROWS 8192
#define DIM   1024
#define THRESH 0.85f

typedef __attribute__((ext_vector_type(4))) float f32x4;
typedef __attribute__((ext_vector_type(8))) short bf16x8;

__device__ __forceinline__ short f2bf(float x) {
    union { float f; unsigned u; } c; c.f = x;
    unsigned r = c.u + 0x7FFFu + ((c.u >> 16) & 1u);
    return (short)(r >> 16);
}

__device__ __forceinline__ float bf2f(short x) {
    union { unsigned u; float f; } c;
    c.u = ((unsigned)(unsigned short)x) << 16;
    return c.f;
}

__device__ __forceinline__ void async16(const void* g, void* l) {
    __builtin_amdgcn_global_load_lds(
        (const __attribute__((address_space(1))) void*)g,
        (__attribute__((address_space(3))) void*)l, 16, 0, 0);
}

// ---------------- merged prep kernel ----------------
// blocks [0, 8192):        summaries f32 -> bf16 (float4/short4)
// blocks [8192, 9216):     transpose W1 -> w1t bf16
// blocks [9216, 10240):    transpose W2 -> w2t bf16
// blocks [10240, 10272):   zero dup
__global__ __launch_bounds__(256) void prep_k(const float* __restrict__ summaries,
                                              short* __restrict__ xb,
                                              const float* __restrict__ W1,
                                              short* __restrict__ w1t,
                                              const float* __restrict__ W2,
                                              short* __restrict__ w2t,
                                              float* __restrict__ dup) {
    __shared__ float tile[32][33];
    const int b = blockIdx.x;
    const int t = threadIdx.x;
    if (b < 8192) {
        const int i = (b * 256 + t) * 4;
        float4 v = *(const float4*)(summaries + i);
        short4 o;
        o.x = f2bf(v.x); o.y = f2bf(v.y); o.z = f2bf(v.z); o.w = f2bf(v.w);
        *(short4*)(xb + i) = o;
    } else if (b < 10240) {
        const int tb = b - 8192;
        const float* in = (tb < 1024) ? W1 : W2;
        short* out = (tb < 1024) ? w1t : w2t;
        const int tid = tb & 1023;
        const int bx = (tid & 31) * 32, by = (tid >> 5) * 32;
        const int tx = t & 31, ty = t >> 5;        // 32 x 8
        for (int r = ty; r < 32; r += 8) tile[r][tx] = in[(size_t)(by + r) * DIM + bx + tx];
        __syncthreads();
        for (int r = ty; r < 32; r += 8) out[(size_t)(bx + r) * DIM + by + tx] = f2bf(tile[tx][r]);
    } else {
        const int i = (b - 10240) * 256 + t;
        if (i < NROWS) dup[i] = 0.f;
    }
}

// LayerNorm + exact GELU + bf16 cast, one row per block. Input h is bf16 (R5).
__global__ __launch_bounds__(256) void ln_gelu_k(const short* __restrict__ h,
                                                 const float* __restrict__ gamma,
                                                 const float* __restrict__ beta,
                                                 short* __restrict__ g) {
    int row = blockIdx.x, t = threadIdx.x;
    short4 hv = *(const short4*)(h + (size_t)row * DIM + t * 4);
    float vv[4] = {bf2f(hv.x), bf2f(hv.y), bf2f(hv.z), bf2f(hv.w)};
    float s = vv[0] + vv[1] + vv[2] + vv[3];
    float ss = vv[0] * vv[0] + vv[1] * vv[1] + vv[2] * vv[2] + vv[3] * vv[3];
    #pragma unroll
    for (int o = 32; o; o >>= 1) { s += __shfl_down(s, o, 64); ss += __shfl_down(ss, o, 64); }
    __shared__ float red[8];
    if ((t & 63) == 0) { red[(t >> 6) * 2] = s; red[(t >> 6) * 2 + 1] = ss; }
    __syncthreads();
    s  = red[0] + red[2] + red[4] + red[6];
    ss = red[1] + red[3] + red[5] + red[7];
    float mu = s * (1.0f / DIM);
    float var = ss * (1.0f / DIM) - mu * mu;
    float rstd = rsqrtf(var + 1e-5f);
    float4 g4 = *(const float4*)(gamma + t * 4);
    float4 b4 = *(const float4*)(beta + t * 4);
    float gg[4] = {g4.x, g4.y, g4.z, g4.w};
    float bb[4] = {b4.x, b4.y, b4.z, b4.w};
    short4 o;
    short* op = (short*)&o;
    #pragma unroll
    for (int i = 0; i < 4; i++) {
        float v = (vv[i] - mu) * rstd * gg[i] + bb[i];
        float ge = 0.5f * v * (1.0f + erff(v * 0.70710678118654752f));
        op[i] = f2bf(ge);
    }
    *(short4*)(g + (size_t)row * DIM + t * 4) = o;
}

// L2 row-normalize + bf16 cast. Input enc is bf16 (R5); normalization is
// self-consistent on the bf16 vector, so |encb| == 1 exactly for the read values.
__global__ __launch_bounds__(256) void rownorm_bf16_k(const short* __restrict__ enc,
                                                      short* __restrict__ out) {
    int row = blockIdx.x, t = threadIdx.x;
    short4 ev = *(const short4*)(enc + (size_t)row * DIM + t * 4);
    float vv[4] = {bf2f(ev.x), bf2f(ev.y), bf2f(ev.z), bf2f(ev.w)};
    float ss = vv[0] * vv[0] + vv[1] * vv[1] + vv[2] * vv[2] + vv[3] * vv[3];
    #pragma unroll
    for (int o = 32; o; o >>= 1) ss += __shfl_down(ss, o, 64);
    __shared__ float red[4];
    if ((t & 63) == 0) red[t >> 6] = ss;
    __syncthreads();
    ss = red[0] + red[1] + red[2] + red[3];
    float inv = 1.0f / fmaxf(sqrtf(ss), 1e-12f);
    short4 o;
    o.x = f2bf(vv[0] * inv); o.y = f2bf(vv[1] * inv);
    o.z = f2bf(vv[2] * inv); o.w = f2bf(vv[3] * inv);
    *(short4*)(out + (size_t)row * DIM + t * 4) = o;
}

#define BARF()   do { asm volatile("" ::: "memory"); __builtin_amdgcn_s_barrier(); asm volatile("" ::: "memory"); } while (0)
#define LGKM0()  asm volatile("s_waitcnt lgkmcnt(0)" ::: "memory")
#define VMCNT(n) asm volatile("s_waitcnt vmcnt(" #n ")" ::: "memory")

// ---------------- dense pipelined GEMM: C[M][N] = A[M][K] @ Bt[N][K]^T + bias ----------------
// BM=128, BN=256, BK=64. 512 threads = 8 waves (2M x 4N), 4-phase counted vmcnt(6).
// Grid (4,64)=256 blocks = 1/CU. Output is bf16 (R5): epilogue converts in-register.
__global__ __launch_bounds__(512, 2) void gemm_dense256_k(const short* __restrict__ A,
                                                          const short* __restrict__ Bt,
                                                          short* __restrict__ C,
                                                          const float* __restrict__ bias,
                                                          int M, int Nmat, int K) {
    extern __shared__ __align__(16) char smraw[];
    short* smA = (short*)smraw;        // 2*2*128*32 shorts = 32 KiB
    short* smB = smA + 16384;          // 2*2*256*32 shorts = 64 KiB
    float* epi = (float*)smraw;        // epilogue reuse: 32 x 260 f32

    const int tileN = blockIdx.x << 8;
    const int tileM = blockIdx.y << 7;

    const int t = threadIdx.x;
    const int wave = t >> 6;
    const int wm = wave >> 2, wn = wave & 3;   // 2M x 4N
    const int l = t & 63;
    const int lr = l & 15, lq = l >> 4;

    const int srow  = t >> 2;
    const int sslot = ((t & 3) ^ ((t >> 3) & 3)) * 8;   // c = s ^ ((row>>1)&3), row = t>>2
    const short* aS  = A  + (size_t)(tileM + srow) * K + sslot;
    const short* bS0 = Bt + (size_t)(tileN + srow) * K + sslot;
    const short* bS1 = bS0 + (size_t)128 * K;
    const int t8 = t * 8;

    const int swz  = (lq ^ ((lr >> 1) & 3)) * 8;
    const int aoff = (wm * 64 + lr) * 32 + swz;
    const int boff = (wn * 64 + lr) * 32 + swz;

    f32x4 acc[4][4];
    #pragma unroll
    for (int i = 0; i < 4; i++)
        #pragma unroll
        for (int j = 0; j < 4; j++) acc[i][j] = (f32x4){0.f, 0.f, 0.f, 0.f};

#define DSTAGE(DB, KH, KC) do { \
    short* da_ = smA + (DB) * 8192 + (KH) * 4096 + t8; \
    async16(aS + (KC), da_); \
    short* db_ = smB + (DB) * 16384 + (KH) * 8192 + t8; \
    async16(bS0 + (KC), db_); async16(bS1 + (KC), db_ + 4096); } while (0)

#define DPH(DB, KH) do { \
    const short* Ab_ = smA + (DB) * 8192 + (KH) * 4096 + aoff; \
    const short* Bb_ = smB + (DB) * 16384 + (KH) * 8192 + boff; \
    af[0] = *(const bf16x8*)(Ab_ + 0);    af[1] = *(const bf16x8*)(Ab_ + 512); \
    af[2] = *(const bf16x8*)(Ab_ + 1024); af[3] = *(const bf16x8*)(Ab_ + 1536); \
    bfr[0] = *(const bf16x8*)(Bb_ + 0);    bfr[1] = *(const bf16x8*)(Bb_ + 512); \
    bfr[2] = *(const bf16x8*)(Bb_ + 1024); bfr[3] = *(const bf16x8*)(Bb_ + 1536); } while (0)

#define DMFMA16() do { \
    __builtin_amdgcn_s_setprio(1); \
    _Pragma("unroll") for (int m_ = 0; m_ < 4; m_++) \
        _Pragma("unroll") for (int n_ = 0; n_ < 4; n_++) \
            acc[m_][n_] = __builtin_amdgcn_mfma_f32_16x16x32_bf16(af[m_], bfr[n_], acc[m_][n_], 0, 0, 0); \
    __builtin_amdgcn_s_setprio(0); } while (0)

    bf16x8 af[4], bfr[4];

    DSTAGE(0, 0, 0);
    DSTAGE(0, 1, 32);
    DSTAGE(1, 0, 64);
    VMCNT(6);
    BARF();

    const int NIT = K >> 7;
    for (int it = 0; it < NIT - 1; ++it) {
        const int kb = it * 128;
        DPH(0, 0); DSTAGE(1, 1, kb + 96);  BARF(); LGKM0(); DMFMA16(); VMCNT(6); BARF();
        DPH(0, 1); DSTAGE(0, 0, kb + 128); BARF(); LGKM0(); DMFMA16(); VMCNT(6); BARF();
        DPH(1, 0); DSTAGE(0, 1, kb + 160); BARF(); LGKM0(); DMFMA16(); VMCNT(6); BARF();
        DPH(1, 1); DSTAGE(1, 0, kb + 192); BARF(); LGKM0(); DMFMA16(); VMCNT(6); BARF();
    }
    {
        const int kb = (NIT - 1) * 128;
        DPH(0, 0); DSTAGE(1, 1, kb + 96);  BARF(); LGKM0(); DMFMA16(); VMCNT(6); BARF();
        DPH(0, 1);                         BARF(); LGKM0(); DMFMA16(); VMCNT(3); BARF();
        DPH(1, 0);                         BARF(); LGKM0(); DMFMA16(); VMCNT(0); BARF();
        DPH(1, 1);                         BARF(); LGKM0(); DMFMA16();           BARF();
    }

#undef DSTAGE
#undef DPH
#undef DMFMA16

    float bj[4];
    #pragma unroll
    for (int nb = 0; nb < 4; nb++) bj[nb] = bias[tileN + wn * 64 + nb * 16 + lr];
    __syncthreads();
    for (int rr = 0; rr < 4; rr++) {
        if (wm == (rr >> 1)) {
            #pragma unroll
            for (int h = 0; h < 2; h++) {
                const int mb = (rr & 1) * 2 + h;
                #pragma unroll
                for (int nb = 0; nb < 4; nb++)
                    #pragma unroll
                    for (int q = 0; q < 4; q++)
                        epi[(h * 16 + lq * 4 + q) * 260 + wn * 64 + nb * 16 + lr] = acc[mb][nb][q] + bj[nb];
            }
        }
        __syncthreads();
        #pragma unroll
        for (int k2 = 0; k2 < 4; k2++) {
            const int v = k2 * 512 + t;
            const int rl = v >> 6;
            const int c4 = (v & 63) * 4;
            float4 vec = *(float4*)&epi[rl * 260 + c4];
            short4 ov;
            ov.x = f2bf(vec.x); ov.y = f2bf(vec.y);
            ov.z = f2bf(vec.z); ov.w = f2bf(vec.w);
            *(short4*)&C[(size_t)(tileM + rr * 32 + rl) * Nmat + tileN + c4] = ov;
        }
        __syncthreads();
    }
}

// ---------------- 256x256 8-phase triangular sim GEMM (T1+T2+T3+T4+T5) ----------------
// Work items: 0..495 = off-diagonal pairs (r<c), 496..527 = diagonal tiles.
// blockIdx 0..511: XCD-chunked swizzle (chunk=64); 512..527 -> diag tail.
__global__ __launch_bounds__(512, 2) void gemm256_tri_k(const short* __restrict__ E,
                                                        float* __restrict__ C,
                                                        float* __restrict__ dup,
                                                        int Nrows, int K) {
    extern __shared__ __align__(16) char smraw[];
    short* smA = (short*)smraw;       // 2*2*256*32 shorts = 65536 B
    short* smB = smA + 32768;         // + 65536 B
    float* epi = (float*)smraw;       // epilogue reuse: 64 x 260 f32

    const int NBT = Nrows >> 8;       // 32
    int w = blockIdx.x;
    if (w < 512) w = (w & 7) * 64 + (w >> 3);
    int bm, bn;
    if (w >= 496) {
        bm = bn = w - 496;
    } else {
        int r = 0, off = 0;
        while (off + (NBT - 1 - r) <= w) { off += NBT - 1 - r; r++; }
        bm = r; bn = r + 1 + (w - off);
    }
    const int tileM = bm << 8, tileN = bn << 8;

    const int t = threadIdx.x;
    const int wave = t >> 6;
    const int wm = wave >> 2, wn = wave & 3;
    const int l = t & 63;
    const int lr = l & 15, lq = l >> 4;

    const int srow  = t >> 2;
    const int sslot = ((t & 3) ^ ((t >> 3) & 3)) * 8;   // c = s ^ ((row>>1)&3)
    const short* aS0 = E + (size_t)(tileM + srow) * K + sslot;
    const short* aS1 = aS0 + (size_t)128 * K;
    const short* bS0 = E + (size_t)(tileN + srow) * K + sslot;
    const short* bS1 = bS0 + (size_t)128 * K;
    const int ldst = t * 8;

    const int swz  = (lq ^ ((lr >> 1) & 3)) * 8;
    const int aoff = (wm * 128 + lr) * 32 + swz;
    const int boff = (wn * 64  + lr) * 32 + swz;

    f32x4 acc[8][4];
    #pragma unroll
    for (int i = 0; i < 8; i++)
        #pragma unroll
        for (int j = 0; j < 4; j++) acc[i][j] = (f32x4){0.f, 0.f, 0.f, 0.f};

#define STAGE_A(DB, KH, KC) do { \
    short* d_ = smA + (DB) * 16384 + (KH) * 8192 + ldst; \
    async16(aS0 + (KC), d_); async16(aS1 + (KC), d_ + 4096); } while (0)
#define STAGE_B(DB, KH, KC) do { \
    short* d_ = smB + (DB) * 16384 + (KH) * 8192 + ldst; \
    async16(bS0 + (KC), d_); async16(bS1 + (KC), d_ + 4096); } while (0)

#define PH_AB(DB, KS, MB) do { \
    const short* Ab_ = smA + (DB) * 16384 + (KS) * 8192 + aoff; \
    const short* Bb_ = smB + (DB) * 16384 + (KS) * 8192 + boff; \
    af[0] = *(const bf16x8*)(Ab_ + ((MB) + 0) * 512); \
    af[1] = *(const bf16x8*)(Ab_ + ((MB) + 1) * 512); \
    af[2] = *(const bf16x8*)(Ab_ + ((MB) + 2) * 512); \
    af[3] = *(const bf16x8*)(Ab_ + ((MB) + 3) * 512); \
    bfr[0] = *(const bf16x8*)(Bb_ + 0);    \
    bfr[1] = *(const bf16x8*)(Bb_ + 512);  \
    bfr[2] = *(const bf16x8*)(Bb_ + 1024); \
    bfr[3] = *(const bf16x8*)(Bb_ + 1536); } while (0)

#define PH_A(DB, KS, MB) do { \
    const short* Ab_ = smA + (DB) * 16384 + (KS) * 8192 + aoff; \
    af[0] = *(const bf16x8*)(Ab_ + ((MB) + 0) * 512); \
    af[1] = *(const bf16x8*)(Ab_ + ((MB) + 1) * 512); \
    af[2] = *(const bf16x8*)(Ab_ + ((MB) + 2) * 512); \
    af[3] = *(const bf16x8*)(Ab_ + ((MB) + 3) * 512); } while (0)

#define MFMA16(MB) do { \
    __builtin_amdgcn_s_setprio(1); \
    _Pragma("unroll") for (int m_ = 0; m_ < 4; m_++) \
        _Pragma("unroll") for (int n_ = 0; n_ < 4; n_++) \
            acc[(MB) + m_][n_] = __builtin_amdgcn_mfma_f32_16x16x32_bf16(af[m_], bfr[n_], acc[(MB) + m_][n_], 0, 0, 0); \
    __builtin_amdgcn_s_setprio(0); } while (0)

    bf16x8 af[4], bfr[4];

    STAGE_A(0, 0, 0);  STAGE_B(0, 0, 0);
    STAGE_A(0, 1, 32); STAGE_B(0, 1, 32);
    STAGE_A(1, 0, 64); STAGE_B(1, 0, 64);
    VMCNT(4);
    BARF();

    const int NIT = K >> 7;
    for (int it = 0; it < NIT - 1; ++it) {
        const int kb = it * 128;
        PH_AB(0, 0, 0); STAGE_A(1, 1, kb + 96);  BARF(); LGKM0(); MFMA16(0); BARF();
        PH_A (0, 0, 4); STAGE_B(1, 1, kb + 96);  BARF(); LGKM0(); MFMA16(4); BARF();
        PH_AB(0, 1, 0); STAGE_A(0, 0, kb + 128); BARF(); LGKM0(); MFMA16(0); BARF();
        PH_A (0, 1, 4); STAGE_B(0, 0, kb + 128); BARF(); LGKM0(); MFMA16(4); VMCNT(4); BARF();
        PH_AB(1, 0, 0); STAGE_A(0, 1, kb + 160); BARF(); LGKM0(); MFMA16(0); BARF();
        PH_A (1, 0, 4); STAGE_B(0, 1, kb + 160); BARF(); LGKM0(); MFMA16(4); BARF();
        PH_AB(1, 1, 0); STAGE_A(1, 0, kb + 192); BARF(); LGKM0(); MFMA16(0); BARF();
        PH_A (1, 1, 4); STAGE_B(1, 0, kb + 192); BARF(); LGKM0(); MFMA16(4); VMCNT(4); BARF();
    }
    {
        const int kb = (NIT - 1) * 128;
        PH_AB(0, 0, 0); STAGE_A(1, 1, kb + 96);  BARF(); LGKM0(); MFMA16(0); BARF();
        PH_A (0, 0, 4); STAGE_B(1, 1, kb + 96);  BARF(); LGKM0(); MFMA16(4); BARF();
        PH_AB(0, 1, 0);                          BARF(); LGKM0(); MFMA16(0); BARF();
        PH_A (0, 1, 4);                          BARF(); LGKM0(); MFMA16(4); VMCNT(0); BARF();
        PH_AB(1, 0, 0);                          BARF(); LGKM0(); MFMA16(0); BARF();
        PH_A (1, 0, 4);                          BARF(); LGKM0(); MFMA16(4); BARF();
        PH_AB(1, 1, 0);                          BARF(); LGKM0(); MFMA16(0); BARF();
        PH_A (1, 1, 4);                          BARF(); LGKM0(); MFMA16(4); BARF();
    }

#undef STAGE_A
#undef STAGE_B
#undef PH_AB
#undef PH_A
#undef MFMA16

    __syncthreads();
    for (int rr = 0; rr < 4; rr++) {
        if ((rr >> 1) == wm) {
            const int mb = (rr & 1) * 4;
            #pragma unroll
            for (int m = 0; m < 4; m++)
                #pragma unroll
                for (int n = 0; n < 4; n++)
                    #pragma unroll
                    for (int q = 0; q < 4; q++)
                        epi[(m * 16 + lq * 4 + q) * 260 + wn * 64 + n * 16 + lr] = acc[mb + m][n][q];
        }
        __syncthreads();
        #pragma unroll
        for (int k2 = 0; k2 < 8; k2++) {
            const int v = k2 * 512 + t;
            const int rl = v >> 6;
            const int c4 = (v & 63) * 4;
            float4 vec = *(float4*)&epi[rl * 260 + c4];
            const int grow = tileM + rr * 64 + rl;
            const int gcol = tileN + c4;
            *(float4*)&C[(size_t)grow * Nrows + gcol] = vec;
            if (vec.x > THRESH && grow < gcol)     dup[gcol]     = 1.f;
            if (vec.y > THRESH && grow < gcol + 1) dup[gcol + 1] = 1.f;
            if (vec.z > THRESH && grow < gcol + 2) dup[gcol + 2] = 1.f;
            if (vec.w > THRESH && grow < gcol + 3) dup[gcol + 3] = 1.f;
        }
        __syncthreads();
    }

    if (bm != bn) {
        for (int cc = 0; cc < 4; cc++) {
            if (wn == cc) {
                #pragma unroll
                for (int i2 = 0; i2 < 8; i2++)
                    #pragma unroll
                    for (int n = 0; n < 4; n++)
                        #pragma unroll
                        for (int q = 0; q < 4; q++)
                            epi[(n * 16 + lr) * 260 + wm * 128 + i2 * 16 + lq * 4 + q] = acc[i2][n][q];
            }
            __syncthreads();
            #pragma unroll
            for (int k2 = 0; k2 < 8; k2++) {
                const int v = k2 * 512 + t;
                const int rl = v >> 6;
                const int c4 = (v & 63) * 4;
                float4 vec = *(float4*)&epi[rl * 260 + c4];
                *(float4*)&C[(size_t)(tileN + cc * 64 + rl) * Nrows + tileM + c4] = vec;
            }
            __syncthreads();
        }
    }
}

// ---------------- launch ----------------

extern "C" void kernel_launch(void* const* d_in, const int* in_sizes, int n_in,
                              void* d_out, int out_size, void* d_ws, size_t ws_size,
                              hipStream_t stream) {
    const float* summaries = (const float*)d_in[0];
    const float* W1    = (const float*)d_in[1];
    const float* b1    = (const float*)d_in[2];
    const float* gamma = (const float*)d_in[3];
    const float* beta  = (const float*)d_in[4];
    const float* W2    = (const float*)d_in[5];
    const float* b2    = (const float*)d_in[6];

    float* sim = (float*)d_out;
    float* dup = sim + (size_t)NROWS * NROWS;

    char* ws = (char*)d_ws;
    short* hb   = (short*)ws;                              // 16 MB: h (bf16), then enc (bf16)
    short* xb   = (short*)(ws + (size_t)32 * 1024 * 1024); // 16 MB: Xb, then encb
    short* gbuf = (short*)(ws + (size_t)48 * 1024 * 1024); // 16 MB: g
    short* w1t  = (short*)(ws + (size_t)64 * 1024 * 1024); // 2 MB
    short* w2t  = (short*)(ws + (size_t)66 * 1024 * 1024); // 2 MB

    static int lds_init = 0;
    if (!lds_init) {
        hipFuncSetAttribute(reinterpret_cast<const void*>(gemm256_tri_k),
                            hipFuncAttributeMaxDynamicSharedMemorySize, 131072);
        hipFuncSetAttribute(reinterpret_cast<const void*>(gemm_dense256_k),
                            hipFuncAttributeMaxDynamicSharedMemorySize, 98304);
        lds_init = 1;
    }

    // merged prep: convert + both transposes + dup zero (one dispatch)
    prep_k<<<dim3(10272), dim3(256), 0, stream>>>(summaries, xb, W1, w1t, W2, w2t, dup);

    // h = X @ W1 + b1  (bf16 out)
    gemm_dense256_k<<<dim3(DIM / 256, NROWS / 128), dim3(512), 98304, stream>>>(
        xb, w1t, hb, b1, NROWS, DIM, DIM);
    // g = gelu(layernorm(h))  (bf16 in/out)
    ln_gelu_k<<<dim3(NROWS), dim3(256), 0, stream>>>(hb, gamma, beta, gbuf);
    // enc = g @ W2 + b2  (bf16 out)
    gemm_dense256_k<<<dim3(DIM / 256, NROWS / 128), dim3(512), 98304, stream>>>(
        gbuf, w2t, hb, b2, NROWS, DIM, DIM);
    // encb = normalize(enc) in bf16  (bf16 in)
    rownorm_bf16_k<<<dim3(NROWS), dim3(256), 0, stream>>>(hb, xb);
    // sim = encb @ encb^T : 256^2 8-phase triangular tiles, diag-last grid
    const int NBT = NROWS / 256;
    gemm256_tri_k<<<dim3(NBT * (NBT + 1) / 2), dim3(512), 131072, stream>>>(
        xb, sim, dup, NROWS, DIM);
}